// Round 4
// baseline (464.147 us; speedup 1.0000x reference)
//
#include <hip/hip_runtime.h>
#include <hip/hip_bf16.h>
#include <cstdint>
#include <cstddef>

typedef float f32x16 __attribute__((ext_vector_type(16)));
typedef float f32x4  __attribute__((ext_vector_type(4)));
typedef float f32x2  __attribute__((ext_vector_type(2)));
typedef short short8 __attribute__((ext_vector_type(8)));
typedef unsigned short us4 __attribute__((ext_vector_type(4)));
typedef unsigned int u32;
typedef unsigned short u16;

#define MFMA32(a,b,c) __builtin_amdgcn_mfma_f32_32x32x16_bf16(a,b,c,0,0,0)
#define MFMA16(a,b,c) __builtin_amdgcn_mfma_f32_16x16x32_bf16(a,b,c,0,0,0)

#define HN 16
#define NQL 2048
#define NKL 2048
#define DM 1024

// 0.125 (1/sqrt(64)) * log2(e), folded into Q at projection time.
#define QSCALE 0.18033688011112042f

static __device__ __forceinline__ u16 f2bf(float f){
  union{float f;u32 u;}x; x.f=f; u32 u=x.u;
  return (u16)((u + 0x7fffu + ((u>>16)&1u))>>16);
}

#define AS1q __attribute__((address_space(1)))
#define AS3q __attribute__((address_space(3)))
static __device__ __forceinline__ void gload16(const void* g, void* l){
  __builtin_amdgcn_global_load_lds((const AS1q u32*)g, (AS3q u32*)l, 16, 0, 0);
}

// ---------------- ws layout (bytes) ----------------
#define OFF_ABF   (size_t)(0)          // 3 * 4096*1024 bf16 = 25165824
#define OFF_BTQKV (size_t)(25165824)   // 3072*1024 bf16 = 6291456
#define OFF_BTO   (size_t)(31457280)   // 1024*1024 bf16 = 2097152
#define OFF_QP    (size_t)(33554432)   // [B,H,2048,64] bf16 = 8388608
#define OFF_KP    (size_t)(41943040)
#define OFF_VT    (size_t)(58720256)   // [B,H,64,2048] bf16
#define OFF_AOUT  (size_t)(67108864)   // [B,2048,1024] bf16
// total 75497472 bytes (72 MB)

// ---------------- cast queries/keys/values -> bf16 ----------------
__global__ void cast3_kernel(const float* __restrict__ q, const float* __restrict__ k,
                             const float* __restrict__ v, u16* __restrict__ dst){
  int i = blockIdx.x*256 + threadIdx.x;              // 3*2^20 float4 units
  const float* src = (i < 1048576) ? q : (i < 2097152 ? k : v);
  int j = i & 1048575;
  float4 val = ((const float4*)src)[j];
  ushort4 o; o.x=f2bf(val.x); o.y=f2bf(val.y); o.z=f2bf(val.z); o.w=f2bf(val.w);
  ((ushort4*)dst)[i] = o;
}

// ---------------- transpose+cast weight matrices ----------------
__global__ void twcast_kernel(const float* __restrict__ wq, const float* __restrict__ wk,
                              const float* __restrict__ wv, const float* __restrict__ wo,
                              u16* __restrict__ btqkv, u16* __restrict__ bto){
  __shared__ float tile[32][33];
  int which = blockIdx.z;
  const float* src = which==0?wq:which==1?wk:which==2?wv:wo;
  u16* dst = which<3 ? btqkv + (size_t)which*1024*1024 : bto;
  int n0 = blockIdx.x*32, k0 = blockIdx.y*32;
  int tx = threadIdx.x, ty = threadIdx.y;
  #pragma unroll
  for (int j=0;j<4;j++) tile[ty+8*j][tx] = src[(size_t)(k0+ty+8*j)*1024 + n0+tx];
  __syncthreads();
  #pragma unroll
  for (int j=0;j<4;j++) dst[(size_t)(n0+ty+8*j)*1024 + k0+tx] = f2bf(tile[tx][ty+8*j]);
}

// ---------------- GEMM0: QKV projection (A 4096x1024 * Bt^T), scatter ----------------
// which=0 -> qp (bias+QSCALE), which=1 -> kp (bias), which=2 -> vt TRANSPOSED (bias)
__global__ __launch_bounds__(256) void gemm0_kernel(
    const u16* __restrict__ Abase, const u16* __restrict__ Bt,
    const float* __restrict__ b0, const float* __restrict__ b1, const float* __restrict__ b2,
    u16* __restrict__ qp, u16* __restrict__ kp, u16* __restrict__ vt)
{
  __shared__ u16 lds[2*128*64];   // A tile [128][64], B tile [128][64], 32 KB
  const int t = threadIdx.x;
  const int lane = t & 63, w = t >> 6;
  const int l15 = lane & 15, l4 = lane >> 4;
  const int n0 = blockIdx.x*128, m0 = blockIdx.y*128;
  const int which = n0 >> 10;
  const u16* A = Abase + (size_t)which*4096*1024;
  const int wr = w >> 1, wc = w & 1;

  f32x4 acc[4][4];
  #pragma unroll
  for (int i=0;i<4;i++)
    #pragma unroll
    for (int j=0;j<4;j++){ acc[i][j][0]=0.f; acc[i][j][1]=0.f; acc[i][j][2]=0.f; acc[i][j][3]=0.f; }

  for (int kk=0; kk<16; kk++){
    #pragma unroll
    for (int i=0;i<4;i++){
      int o = i*4096 + w*1024 + lane*16;
      int row = o >> 7, c16 = (o >> 4) & 7;
      int c16s = c16 ^ (row & 7);
      gload16(A + ((size_t)(m0+row)*1024 + kk*64 + c16s*8), (char*)lds + (i*4096 + w*1024));
    }
    #pragma unroll
    for (int i=0;i<4;i++){
      int o = i*4096 + w*1024 + lane*16;
      int row = o >> 7, c16 = (o >> 4) & 7;
      int c16s = c16 ^ (row & 7);
      gload16(Bt + ((size_t)(n0+row)*1024 + kk*64 + c16s*8), (char*)lds + 16384 + (i*4096 + w*1024));
    }
    __syncthreads();

    short8 af[4][2], bf[4][2];
    #pragma unroll
    for (int mr=0;mr<4;mr++)
      #pragma unroll
      for (int ks=0;ks<2;ks++){
        int row = wr*64 + mr*16 + l15;
        int c16 = ks*4 + l4;
        af[mr][ks] = *(const short8*)((const char*)lds + row*128 + ((c16 ^ (row&7))*16));
      }
    #pragma unroll
    for (int nc=0;nc<4;nc++)
      #pragma unroll
      for (int ks=0;ks<2;ks++){
        int row = wc*64 + nc*16 + l15;
        int c16 = ks*4 + l4;
        bf[nc][ks] = *(const short8*)((const char*)lds + 16384 + row*128 + ((c16 ^ (row&7))*16));
      }
    #pragma unroll
    for (int ks=0;ks<2;ks++)
      #pragma unroll
      for (int mr=0;mr<4;mr++)
        #pragma unroll
        for (int nc=0;nc<4;nc++)
          acc[mr][nc] = MFMA16(af[mr][ks], bf[nc][ks], acc[mr][nc]);
    __syncthreads();
  }

  if (which < 2){
    const float* bias = which==0?b0:b1;
    u16* dst = which==0?qp:kp;
    const float sc = (which==0) ? QSCALE : 1.0f;
    #pragma unroll
    for (int mr=0;mr<4;mr++)
      #pragma unroll
      for (int nc=0;nc<4;nc++)
        #pragma unroll
        for (int r=0;r<4;r++){
          int grow = m0 + wr*64 + mr*16 + l4*4 + r;
          int gcol = n0 + wc*64 + nc*16 + l15;
          int c1024 = gcol & 1023;
          float val = (acc[mr][nc][r] + bias[c1024]) * sc;
          int bsel = grow >> 11, nn = grow & 2047;
          int hh = c1024 >> 6, dd = gcol & 63;
          dst[((size_t)(bsel*HN+hh)*NQL + nn)*64 + dd] = f2bf(val);
        }
  } else {
    // V: write transposed directly -> vt[b*16+h][d][n], 4 consecutive n per lane
    #pragma unroll
    for (int mr=0;mr<4;mr++)
      #pragma unroll
      for (int nc=0;nc<4;nc++){
        int grow0 = m0 + wr*64 + mr*16 + l4*4;   // 4 consecutive rows, 2048-aligned base
        int gcol = n0 + wc*64 + nc*16 + l15;
        int c1024 = gcol & 1023;
        int bsel = grow0 >> 11, nn = grow0 & 2047;
        int hh = c1024 >> 6, dd = c1024 & 63;
        float bv_ = b2[c1024];
        us4 pk;
        pk.x = f2bf(acc[mr][nc][0] + bv_);
        pk.y = f2bf(acc[mr][nc][1] + bv_);
        pk.z = f2bf(acc[mr][nc][2] + bv_);
        pk.w = f2bf(acc[mr][nc][3] + bv_);
        *(us4*)(vt + ((size_t)(bsel*HN+hh)*64 + dd)*NKL + nn) = pk;
      }
  }
}

// ---------------- GEMM1: out = aout(4096x1024 bf16) @ bto^T + bo, f32 out ----------------
// 64x128 tile, 4 waves (2x2), 512 blocks = 2/CU for barrier-drain overlap.
__global__ __launch_bounds__(256) void gemm1_kernel(
    const u16* __restrict__ A, const u16* __restrict__ Bt,
    const float* __restrict__ bo, float* __restrict__ out)
{
  __shared__ u16 lds[(64+128)*64];   // A [64][64] @0, B [128][64] @8KB; 24 KB
  const int t = threadIdx.x;
  const int lane = t & 63, w = t >> 6;
  const int l15 = lane & 15, l4 = lane >> 4;
  const int n0 = blockIdx.x*128, m0 = blockIdx.y*64;
  const int wr = w >> 1, wc = w & 1;

  f32x4 acc[2][4];
  #pragma unroll
  for (int i=0;i<2;i++)
    #pragma unroll
    for (int j=0;j<4;j++){ acc[i][j][0]=0.f; acc[i][j][1]=0.f; acc[i][j][2]=0.f; acc[i][j][3]=0.f; }

  for (int kk=0; kk<16; kk++){
    // stage A (8 KB): 2 insts/thread
    #pragma unroll
    for (int i=0;i<2;i++){
      int o = i*4096 + w*1024 + lane*16;
      int row = o >> 7, c16 = (o >> 4) & 7;
      int c16s = c16 ^ (row & 7);
      gload16(A + ((size_t)(m0+row)*1024 + kk*64 + c16s*8), (char*)lds + (i*4096 + w*1024));
    }
    // stage B (16 KB): 4 insts/thread
    #pragma unroll
    for (int i=0;i<4;i++){
      int o = i*4096 + w*1024 + lane*16;
      int row = o >> 7, c16 = (o >> 4) & 7;
      int c16s = c16 ^ (row & 7);
      gload16(Bt + ((size_t)(n0+row)*1024 + kk*64 + c16s*8), (char*)lds + 8192 + (i*4096 + w*1024));
    }
    __syncthreads();

    short8 af[2][2], bf[4][2];
    #pragma unroll
    for (int mr=0;mr<2;mr++)
      #pragma unroll
      for (int ks=0;ks<2;ks++){
        int row = wr*32 + mr*16 + l15;
        int c16 = ks*4 + l4;
        af[mr][ks] = *(const short8*)((const char*)lds + row*128 + ((c16 ^ (row&7))*16));
      }
    #pragma unroll
    for (int nc=0;nc<4;nc++)
      #pragma unroll
      for (int ks=0;ks<2;ks++){
        int row = wc*64 + nc*16 + l15;
        int c16 = ks*4 + l4;
        bf[nc][ks] = *(const short8*)((const char*)lds + 8192 + row*128 + ((c16 ^ (row&7))*16));
      }
    #pragma unroll
    for (int ks=0;ks<2;ks++)
      #pragma unroll
      for (int mr=0;mr<2;mr++)
        #pragma unroll
        for (int nc=0;nc<4;nc++)
          acc[mr][nc] = MFMA16(af[mr][ks], bf[nc][ks], acc[mr][nc]);
    __syncthreads();
  }

  #pragma unroll
  for (int mr=0;mr<2;mr++)
    #pragma unroll
    for (int nc=0;nc<4;nc++)
      #pragma unroll
      for (int r=0;r<4;r++){
        int grow = m0 + wr*32 + mr*16 + l4*4 + r;
        int gcol = n0 + wc*64 + nc*16 + l15;
        out[(size_t)grow*1024 + gcol] = acc[mr][nc][r] + bo[gcol];
      }
}

// ---------------- flash attention, flat softmax (no max), W-prefetch ----------------
__global__ __launch_bounds__(64) void attn_kernel(
  const u16* __restrict__ qp, const u16* __restrict__ kp, const u16* __restrict__ vt,
  const float* __restrict__ wts, u16* __restrict__ aout)
{
  __shared__ u16 plds[32*64];     // P tile [32 q][64 n], XOR-swizzled rows of 128 B
  const int lane = threadIdx.x;
  const int lo = lane & 31, hi = lane >> 5;
  // XCD swizzle: XCD i (= g%8) serves bh in [4i, 4i+4) -> 2 MB K/V per XCD L2
  const int g = blockIdx.x;
  const int jj = g >> 3;
  const int bh = (g & 7)*4 + (jj >> 6);
  const int qt = jj & 63;
  const int b = bh >> 4;
  const int q0 = qt*32;

  const u16* qb = qp + ((size_t)bh*NQL + q0)*64;
  const u16* kb = kp + (size_t)bh*NKL*64;
  const u16* vb = vt + (size_t)bh*64*NKL;
  const float* wb = wts + ((size_t)bh*NQL + q0)*(size_t)NKL;

  short8 qf[4];
  #pragma unroll
  for (int ks=0;ks<4;ks++)
    qf[ks] = *(const short8*)(qb + (size_t)lo*64 + ks*16 + hi*8);

  f32x16 o0, o1;
  float ls[16];
  #pragma unroll
  for (int r=0;r<16;r++){ o0[r]=0.f; o1[r]=0.f; ls[r]=0.f; }

  float wx[2][16], wy[2][16];
  #pragma unroll
  for (int r=0;r<16;r++){
    int qr = (r&3) + 8*(r>>2) + 4*hi;
    const f32x2* wp = (const f32x2*)(wb + (size_t)qr*NKL) + lo;
    f32x2 wv = __builtin_nontemporal_load(wp);
    wx[0][r] = wv.x; wy[0][r] = wv.y;
  }

  #pragma unroll 2
  for (int kt=0; kt<32; kt++){
    const int cur = kt & 1;
    const int kb0 = kt*64;
    short8 kf0[4], kf1[4], vf0[4], vf1[4];
    #pragma unroll
    for (int ks=0;ks<4;ks++){
      kf0[ks] = *(const short8*)(kb + (size_t)(kb0+2*lo  )*64 + ks*16 + hi*8);
      kf1[ks] = *(const short8*)(kb + (size_t)(kb0+2*lo+1)*64 + ks*16 + hi*8);
    }
    #pragma unroll
    for (int ks=0;ks<4;ks++){
      vf0[ks] = *(const short8*)(vb + (size_t)lo*NKL      + kb0 + ks*16 + hi*8);
      vf1[ks] = *(const short8*)(vb + (size_t)(32+lo)*NKL + kb0 + ks*16 + hi*8);
    }
    if (kt < 31){
      #pragma unroll
      for (int r=0;r<16;r++){
        int qr = (r&3) + 8*(r>>2) + 4*hi;
        const f32x2* wp = (const f32x2*)(wb + (size_t)qr*NKL + kb0 + 64) + lo;
        f32x2 wv = __builtin_nontemporal_load(wp);
        wx[cur^1][r] = wv.x; wy[cur^1][r] = wv.y;
      }
    }
    f32x16 s0, s1;
    #pragma unroll
    for (int r=0;r<16;r++){ s0[r]=0.f; s1[r]=0.f; }
    #pragma unroll
    for (int ks=0;ks<4;ks++){
      s0 = MFMA32(qf[ks], kf0[ks], s0);
      s1 = MFMA32(qf[ks], kf1[ks], s1);
    }
    #pragma unroll
    for (int r=0;r<16;r++){
      float p0 = exp2f(s0[r] * wx[cur][r]);
      float p1 = exp2f(s1[r] * wy[cur][r]);
      ls[r] += p0 + p1;
      u32 pk;
      asm("v_cvt_pk_bf16_f32 %0, %1, %2" : "=v"(pk) : "v"(p0), "v"(p1));
      int row = (r&3) + 8*(r>>2) + 4*hi;
      *(u32*)((char*)plds + row*128 + ((lo*4) ^ ((row&7)<<4))) = pk;
    }
    short8 pf[4];
    #pragma unroll
    for (int t=0;t<4;t++)
      pf[t] = *(const short8*)((const char*)plds + lo*128 + ((t*32 + hi*16) ^ ((lo&7)<<4)));
    #pragma unroll
    for (int t=0;t<4;t++){
      o0 = MFMA32(pf[t], vf0[t], o0);
      o1 = MFMA32(pf[t], vf1[t], o1);
    }
  }

  u16* ob = aout + ((size_t)b*NQL + q0)*DM + (bh & 15)*64;
  #pragma unroll
  for (int r=0;r<16;r++){
    float L = ls[r];
    L += __shfl_xor(L,1); L += __shfl_xor(L,2); L += __shfl_xor(L,4);
    L += __shfl_xor(L,8); L += __shfl_xor(L,16);
    float inv = 1.0f / L;
    int q = (r&3) + 8*(r>>2) + 4*hi;
    ob[(size_t)q*DM + lo]      = f2bf(o0[r]*inv);
    ob[(size_t)q*DM + 32 + lo] = f2bf(o1[r]*inv);
  }
}

// ---------------- launcher ----------------
extern "C" void kernel_launch(void* const* d_in, const int* in_sizes, int n_in,
                              void* d_out, int out_size, void* d_ws, size_t ws_size,
                              hipStream_t stream){
  const float* queries = (const float*)d_in[0];
  const float* keys    = (const float*)d_in[1];
  const float* values  = (const float*)d_in[2];
  const float* attw    = (const float*)d_in[3];
  const float* Wq = (const float*)d_in[4];
  const float* bq = (const float*)d_in[5];
  const float* Wk = (const float*)d_in[6];
  const float* bk = (const float*)d_in[7];
  const float* Wv = (const float*)d_in[8];
  const float* bv = (const float*)d_in[9];
  const float* Wo = (const float*)d_in[10];
  const float* bo = (const float*)d_in[11];
  char* ws = (char*)d_ws;
  u16* abf   = (u16*)(ws + OFF_ABF);
  u16* btqkv = (u16*)(ws + OFF_BTQKV);
  u16* bto   = (u16*)(ws + OFF_BTO);
  u16* qp    = (u16*)(ws + OFF_QP);
  u16* kp    = (u16*)(ws + OFF_KP);
  u16* vt    = (u16*)(ws + OFF_VT);
  u16* aout  = (u16*)(ws + OFF_AOUT);
  float* out = (float*)d_out;

  cast3_kernel<<<12288, 256, 0, stream>>>(queries, keys, values, abf);
  twcast_kernel<<<dim3(32,32,4), dim3(32,8), 0, stream>>>(Wq,Wk,Wv,Wo,btqkv,bto);
  gemm0_kernel<<<dim3(24,32), 256, 0, stream>>>(abf, btqkv, bq,bk,bv, qp,kp,vt);
  // MEASUREMENT: attn launched TWICE (idempotent). attn_dur ~= dur_this_round
  //  - dur_prev + savings(tv fusion + gemm1 retile). Remove the dup next round.
  attn_kernel<<<2048, 64, 0, stream>>>(qp, kp, vt, attw, aout);
  attn_kernel<<<2048, 64, 0, stream>>>(qp, kp, vt, attw, aout);
  gemm1_kernel<<<dim3(8,64), 256, 0, stream>>>(aout, bto, bo, out);
}

// Round 5
// 238.135 us; speedup vs baseline: 1.9491x; 1.9491x over previous
//
#include <hip/hip_runtime.h>
#include <hip/hip_bf16.h>
#include <cstdint>
#include <cstddef>

typedef float f32x16 __attribute__((ext_vector_type(16)));
typedef float f32x4  __attribute__((ext_vector_type(4)));
typedef float f32x2  __attribute__((ext_vector_type(2)));
typedef short short8 __attribute__((ext_vector_type(8)));
typedef unsigned short us4 __attribute__((ext_vector_type(4)));
typedef unsigned int u32;
typedef unsigned short u16;

#define MFMA32(a,b,c) __builtin_amdgcn_mfma_f32_32x32x16_bf16(a,b,c,0,0,0)
#define MFMA16(a,b,c) __builtin_amdgcn_mfma_f32_16x16x32_bf16(a,b,c,0,0,0)

#define HN 16
#define NQL 2048
#define NKL 2048
#define DM 1024

// 0.125 (1/sqrt(64)) * log2(e), folded into Q at projection time.
#define QSCALE 0.18033688011112042f

static __device__ __forceinline__ u16 f2bf(float f){
  union{float f;u32 u;}x; x.f=f; u32 u=x.u;
  return (u16)((u + 0x7fffu + ((u>>16)&1u))>>16);
}

#define AS1q __attribute__((address_space(1)))
#define AS3q __attribute__((address_space(3)))
static __device__ __forceinline__ void gload16(const void* g, void* l){
  __builtin_amdgcn_global_load_lds((const AS1q u32*)g, (AS3q u32*)l, 16, 0, 0);
}

// ---------------- ws layout (bytes) ----------------
#define OFF_ABF   (size_t)(0)          // 3 * 4096*1024 bf16 = 25165824
#define OFF_BTQKV (size_t)(25165824)   // 3072*1024 bf16 = 6291456
#define OFF_BTO   (size_t)(31457280)   // 1024*1024 bf16 = 2097152
#define OFF_QP    (size_t)(33554432)   // [B,H,2048,64] bf16 = 8388608
#define OFF_KP    (size_t)(41943040)
#define OFF_VT    (size_t)(58720256)   // [B,H,64,2048] bf16
#define OFF_AOUT  (size_t)(67108864)   // [B,2048,1024] bf16
// total 75497472 bytes (72 MB)

// ---------------- cast queries/keys/values -> bf16 ----------------
__global__ void cast3_kernel(const float* __restrict__ q, const float* __restrict__ k,
                             const float* __restrict__ v, u16* __restrict__ dst){
  int i = blockIdx.x*256 + threadIdx.x;              // 3*2^20 float4 units
  const float* src = (i < 1048576) ? q : (i < 2097152 ? k : v);
  int j = i & 1048575;
  float4 val = ((const float4*)src)[j];
  ushort4 o; o.x=f2bf(val.x); o.y=f2bf(val.y); o.z=f2bf(val.z); o.w=f2bf(val.w);
  ((ushort4*)dst)[i] = o;
}

// ---------------- transpose+cast weight matrices ----------------
__global__ void twcast_kernel(const float* __restrict__ wq, const float* __restrict__ wk,
                              const float* __restrict__ wv, const float* __restrict__ wo,
                              u16* __restrict__ btqkv, u16* __restrict__ bto){
  __shared__ float tile[32][33];
  int which = blockIdx.z;
  const float* src = which==0?wq:which==1?wk:which==2?wv:wo;
  u16* dst = which<3 ? btqkv + (size_t)which*1024*1024 : bto;
  int n0 = blockIdx.x*32, k0 = blockIdx.y*32;
  int tx = threadIdx.x, ty = threadIdx.y;
  #pragma unroll
  for (int j=0;j<4;j++) tile[ty+8*j][tx] = src[(size_t)(k0+ty+8*j)*1024 + n0+tx];
  __syncthreads();
  #pragma unroll
  for (int j=0;j<4;j++) dst[(size_t)(n0+ty+8*j)*1024 + k0+tx] = f2bf(tile[tx][ty+8*j]);
}

// ---------------- GEMM0: QKV projection (A 4096x1024 * Bt^T), scatter ----------------
// which=0 -> qp (bias+QSCALE), which=1 -> kp (bias), which=2 -> vt TRANSPOSED (bias)
__global__ __launch_bounds__(256) void gemm0_kernel(
    const u16* __restrict__ Abase, const u16* __restrict__ Bt,
    const float* __restrict__ b0, const float* __restrict__ b1, const float* __restrict__ b2,
    u16* __restrict__ qp, u16* __restrict__ kp, u16* __restrict__ vt)
{
  __shared__ u16 lds[2*128*64];   // A tile [128][64], B tile [128][64], 32 KB
  const int t = threadIdx.x;
  const int lane = t & 63, w = t >> 6;
  const int l15 = lane & 15, l4 = lane >> 4;
  const int n0 = blockIdx.x*128, m0 = blockIdx.y*128;
  const int which = n0 >> 10;
  const u16* A = Abase + (size_t)which*4096*1024;
  const int wr = w >> 1, wc = w & 1;

  f32x4 acc[4][4];
  #pragma unroll
  for (int i=0;i<4;i++)
    #pragma unroll
    for (int j=0;j<4;j++){ acc[i][j][0]=0.f; acc[i][j][1]=0.f; acc[i][j][2]=0.f; acc[i][j][3]=0.f; }

  for (int kk=0; kk<16; kk++){
    #pragma unroll
    for (int i=0;i<4;i++){
      int o = i*4096 + w*1024 + lane*16;
      int row = o >> 7, c16 = (o >> 4) & 7;
      int c16s = c16 ^ (row & 7);
      gload16(A + ((size_t)(m0+row)*1024 + kk*64 + c16s*8), (char*)lds + (i*4096 + w*1024));
    }
    #pragma unroll
    for (int i=0;i<4;i++){
      int o = i*4096 + w*1024 + lane*16;
      int row = o >> 7, c16 = (o >> 4) & 7;
      int c16s = c16 ^ (row & 7);
      gload16(Bt + ((size_t)(n0+row)*1024 + kk*64 + c16s*8), (char*)lds + 16384 + (i*4096 + w*1024));
    }
    __syncthreads();

    short8 af[4][2], bf[4][2];
    #pragma unroll
    for (int mr=0;mr<4;mr++)
      #pragma unroll
      for (int ks=0;ks<2;ks++){
        int row = wr*64 + mr*16 + l15;
        int c16 = ks*4 + l4;
        af[mr][ks] = *(const short8*)((const char*)lds + row*128 + ((c16 ^ (row&7))*16));
      }
    #pragma unroll
    for (int nc=0;nc<4;nc++)
      #pragma unroll
      for (int ks=0;ks<2;ks++){
        int row = wc*64 + nc*16 + l15;
        int c16 = ks*4 + l4;
        bf[nc][ks] = *(const short8*)((const char*)lds + 16384 + row*128 + ((c16 ^ (row&7))*16));
      }
    #pragma unroll
    for (int ks=0;ks<2;ks++)
      #pragma unroll
      for (int mr=0;mr<4;mr++)
        #pragma unroll
        for (int nc=0;nc<4;nc++)
          acc[mr][nc] = MFMA16(af[mr][ks], bf[nc][ks], acc[mr][nc]);
    __syncthreads();
  }

  if (which < 2){
    const float* bias = which==0?b0:b1;
    u16* dst = which==0?qp:kp;
    const float sc = (which==0) ? QSCALE : 1.0f;
    #pragma unroll
    for (int mr=0;mr<4;mr++)
      #pragma unroll
      for (int nc=0;nc<4;nc++)
        #pragma unroll
        for (int r=0;r<4;r++){
          int grow = m0 + wr*64 + mr*16 + l4*4 + r;
          int gcol = n0 + wc*64 + nc*16 + l15;
          int c1024 = gcol & 1023;
          float val = (acc[mr][nc][r] + bias[c1024]) * sc;
          int bsel = grow >> 11, nn = grow & 2047;
          int hh = c1024 >> 6, dd = gcol & 63;
          dst[((size_t)(bsel*HN+hh)*NQL + nn)*64 + dd] = f2bf(val);
        }
  } else {
    // V: write transposed directly -> vt[b*16+h][d][n], 4 consecutive n per lane
    #pragma unroll
    for (int mr=0;mr<4;mr++)
      #pragma unroll
      for (int nc=0;nc<4;nc++){
        int grow0 = m0 + wr*64 + mr*16 + l4*4;
        int gcol = n0 + wc*64 + nc*16 + l15;
        int c1024 = gcol & 1023;
        int bsel = grow0 >> 11, nn = grow0 & 2047;
        int hh = c1024 >> 6, dd = c1024 & 63;
        float bv_ = b2[c1024];
        us4 pk;
        pk.x = f2bf(acc[mr][nc][0] + bv_);
        pk.y = f2bf(acc[mr][nc][1] + bv_);
        pk.z = f2bf(acc[mr][nc][2] + bv_);
        pk.w = f2bf(acc[mr][nc][3] + bv_);
        *(us4*)(vt + ((size_t)(bsel*HN+hh)*64 + dd)*NKL + nn) = pk;
      }
  }
}

// ---------------- GEMM1: out = aout(4096x1024 bf16) @ bto^T + bo, f32 out ----------------
__global__ __launch_bounds__(256) void gemm1_kernel(
    const u16* __restrict__ A, const u16* __restrict__ Bt,
    const float* __restrict__ bo, float* __restrict__ out)
{
  __shared__ u16 lds[(64+128)*64];   // A [64][64] @0, B [128][64] @8KB; 24 KB
  const int t = threadIdx.x;
  const int lane = t & 63, w = t >> 6;
  const int l15 = lane & 15, l4 = lane >> 4;
  const int n0 = blockIdx.x*128, m0 = blockIdx.y*64;
  const int wr = w >> 1, wc = w & 1;

  f32x4 acc[2][4];
  #pragma unroll
  for (int i=0;i<2;i++)
    #pragma unroll
    for (int j=0;j<4;j++){ acc[i][j][0]=0.f; acc[i][j][1]=0.f; acc[i][j][2]=0.f; acc[i][j][3]=0.f; }

  for (int kk=0; kk<16; kk++){
    #pragma unroll
    for (int i=0;i<2;i++){
      int o = i*4096 + w*1024 + lane*16;
      int row = o >> 7, c16 = (o >> 4) & 7;
      int c16s = c16 ^ (row & 7);
      gload16(A + ((size_t)(m0+row)*1024 + kk*64 + c16s*8), (char*)lds + (i*4096 + w*1024));
    }
    #pragma unroll
    for (int i=0;i<4;i++){
      int o = i*4096 + w*1024 + lane*16;
      int row = o >> 7, c16 = (o >> 4) & 7;
      int c16s = c16 ^ (row & 7);
      gload16(Bt + ((size_t)(n0+row)*1024 + kk*64 + c16s*8), (char*)lds + 8192 + (i*4096 + w*1024));
    }
    __syncthreads();

    short8 af[2][2], bf[4][2];
    #pragma unroll
    for (int mr=0;mr<2;mr++)
      #pragma unroll
      for (int ks=0;ks<2;ks++){
        int row = wr*32 + mr*16 + l15;
        int c16 = ks*4 + l4;
        af[mr][ks] = *(const short8*)((const char*)lds + row*128 + ((c16 ^ (row&7))*16));
      }
    #pragma unroll
    for (int nc=0;nc<4;nc++)
      #pragma unroll
      for (int ks=0;ks<2;ks++){
        int row = wc*64 + nc*16 + l15;
        int c16 = ks*4 + l4;
        bf[nc][ks] = *(const short8*)((const char*)lds + 8192 + row*128 + ((c16 ^ (row&7))*16));
      }
    #pragma unroll
    for (int ks=0;ks<2;ks++)
      #pragma unroll
      for (int mr=0;mr<2;mr++)
        #pragma unroll
        for (int nc=0;nc<4;nc++)
          acc[mr][nc] = MFMA16(af[mr][ks], bf[nc][ks], acc[mr][nc]);
    __syncthreads();
  }

  #pragma unroll
  for (int mr=0;mr<2;mr++)
    #pragma unroll
    for (int nc=0;nc<4;nc++)
      #pragma unroll
      for (int r=0;r<4;r++){
        int grow = m0 + wr*32 + mr*16 + l4*4 + r;
        int gcol = n0 + wc*64 + nc*16 + l15;
        out[(size_t)grow*1024 + gcol] = acc[mr][nc][r] + bo[gcol];
      }
}

// ---------------- flash attention v3: 4-wave blocks, LDS-staged K/V/W ----------------
// Block = 4 q-tiles (128 q rows) of one head. K/V double-buffered swizzled LDS
// (shared, global_load_lds). W per-wave LDS slab (read->overwrite prefetch).
// Flat softmax (no max; Q pre-scaled by 0.125*log2e), n-interleave 2lo/2lo+1.
__global__ __launch_bounds__(256) void attn_kernel(
  const u16* __restrict__ qp, const u16* __restrict__ kp, const u16* __restrict__ vt,
  const float* __restrict__ wts, u16* __restrict__ aout)
{
  __shared__ __align__(16) char lds[81920];
  // kl: 0..16K (2x8KB), vl: 16K..32K (2x8KB), wl: 32K + wid*8KB, pl: 64K... see below
  char* kl = lds;
  char* vl = lds + 16384;
  const int tid = threadIdx.x;
  const int lane = tid & 63, wid = tid >> 6;
  const int lo = lane & 31, hi = lane >> 5;
  char* wl = lds + 32768 + wid*8192;
  char* pl = lds + 65536 + wid*4096;

  // XCD swizzle: XCD (g&7) owns heads [4x, 4x+4) -> ~2MB K/V per XCD L2
  const int g = blockIdx.x;
  const int j = g >> 3;
  const int bh = (g & 7)*4 + (j >> 4);
  const int qblk = j & 15;
  const int b = bh >> 4;
  const int q0 = qblk*128 + wid*32;

  const u16* qb = qp + ((size_t)bh*NQL + q0)*64;
  const u16* kb = kp + (size_t)bh*NKL*64;
  const u16* vb = vt + (size_t)bh*64*NKL;
  const float* wb = wts + ((size_t)bh*NQL + q0)*(size_t)NKL;

  // Q fragments (A-operand): row q = lo, d-slice ks*16 + hi*8
  short8 qf[4];
  #pragma unroll
  for (int ks=0;ks<4;ks++)
    qf[ks] = *(const short8*)(qb + (size_t)lo*64 + ks*16 + hi*8);

  f32x16 o0, o1;
  float ls[16];
  #pragma unroll
  for (int r=0;r<16;r++){ o0[r]=0.f; o1[r]=0.f; ls[r]=0.f; }

  const int le8 = lane & 7, ld8 = lane >> 3;      // for K/V staging
  const int le16 = lane & 15, ld16 = lane >> 4;   // for W staging

  // ---- prologue: stage tile 0 ----
  {
    #pragma unroll
    for (int s=0;s<2;s++){
      int i = wid*2 + s;
      int row = 8*i + ld8;
      int slot = le8 ^ ((row>>1)&7);
      gload16(kb + (size_t)row*64 + slot*8, kl + i*1024);
      int dslot = le8 ^ (ld8&7);
      gload16(vb + (size_t)row*NKL + dslot*8, vl + i*1024);
    }
    #pragma unroll
    for (int i=0;i<8;i++){
      int q = 4*i + ld16;
      gload16(wb + (size_t)q*NKL + le16*4, wl + i*1024);
    }
  }
  __syncthreads();

  for (int kt=0; kt<32; kt++){
    const int cur = (kt&1)*8192;
    const int nxt = cur ^ 8192;
    const int kb0 = kt*64;

    // W[cur] -> regs (per-wave slab; must drain before overwrite-prefetch)
    f32x2 wp[16];
    #pragma unroll
    for (int r=0;r<16;r++){
      int qr = (r&3) + 8*(r>>2) + 4*hi;
      wp[r] = *(const f32x2*)(wl + qr*256 + lo*8);
    }
    // K fragments from swizzled LDS: rows 2lo (kf0), 2lo+1 (kf1)
    short8 kf0[4], kf1[4];
    #pragma unroll
    for (int ks=0;ks<4;ks++){
      int slot = (ks*2 + hi) ^ (lo&7);
      kf0[ks] = *(const short8*)(kl + cur + (2*lo)*128 + slot*16);
      kf1[ks] = *(const short8*)(kl + cur + (2*lo)*128 + 128 + slot*16);
    }
    asm volatile("s_waitcnt lgkmcnt(0)" ::: "memory");
    __builtin_amdgcn_sched_barrier(0);

    // prefetch next tile (K/V -> nxt buf, W -> same slab)
    if (kt < 31){
      int kb1 = kb0 + 64;
      #pragma unroll
      for (int s=0;s<2;s++){
        int i = wid*2 + s;
        int row = 8*i + ld8;
        int slot = le8 ^ ((row>>1)&7);
        gload16(kb + (size_t)(kb1+row)*64 + slot*8, kl + nxt + i*1024);
        int dslot = le8 ^ (ld8&7);
        gload16(vb + (size_t)row*NKL + kb1 + dslot*8, vl + nxt + i*1024);
      }
      #pragma unroll
      for (int i=0;i<8;i++){
        int q = 4*i + ld16;
        gload16(wb + (size_t)q*NKL + kb1 + le16*4, wl + i*1024);
      }
    }

    // QK^T
    f32x16 s0, s1;
    #pragma unroll
    for (int r=0;r<16;r++){ s0[r]=0.f; s1[r]=0.f; }
    #pragma unroll
    for (int ks=0;ks<4;ks++){
      s0 = MFMA32(qf[ks], kf0[ks], s0);
      s1 = MFMA32(qf[ks], kf1[ks], s1);
    }

    // V fragments from swizzled LDS: rows d=lo (vf0), d=32+lo (vf1)
    short8 vf0[4], vf1[4];
    #pragma unroll
    for (int t=0;t<4;t++){
      int slot = (t*2 + hi) ^ (lo&7);
      vf0[t] = *(const short8*)(vl + cur + lo*128 + slot*16);
      vf1[t] = *(const short8*)(vl + cur + (32+lo)*128 + slot*16);
    }

    // flat softmax: p = exp2(s*w); pack to bf16 P tile (swizzled)
    #pragma unroll
    for (int r=0;r<16;r++){
      float p0 = exp2f(s0[r] * wp[r].x);
      float p1 = exp2f(s1[r] * wp[r].y);
      ls[r] += p0 + p1;
      u32 pk;
      asm("v_cvt_pk_bf16_f32 %0, %1, %2" : "=v"(pk) : "v"(p0), "v"(p1));
      int row = (r&3) + 8*(r>>2) + 4*hi;
      *(u32*)(pl + row*128 + ((lo*4) ^ ((row&7)<<4))) = pk;
    }
    asm volatile("s_waitcnt lgkmcnt(0)" ::: "memory");
    // P fragments (A-operand): row q = lo
    short8 pf[4];
    #pragma unroll
    for (int t=0;t<4;t++)
      pf[t] = *(const short8*)(pl + lo*128 + ((t*32 + hi*16) ^ ((lo&7)<<4)));
    #pragma unroll
    for (int t=0;t<4;t++){
      o0 = MFMA32(pf[t], vf0[t], o0);
      o1 = MFMA32(pf[t], vf1[t], o1);
    }
    __syncthreads();   // drains vmcnt (staged tiles) + barrier
  }

  // epilogue: rowsum reduce, divide, store bf16
  u16* ob = aout + ((size_t)b*NQL + q0)*DM + (bh & 15)*64;
  #pragma unroll
  for (int r=0;r<16;r++){
    float L = ls[r];
    L += __shfl_xor(L,1); L += __shfl_xor(L,2); L += __shfl_xor(L,4);
    L += __shfl_xor(L,8); L += __shfl_xor(L,16);
    float inv = 1.0f / L;
    int q = (r&3) + 8*(r>>2) + 4*hi;
    ob[(size_t)q*DM + lo]      = f2bf(o0[r]*inv);
    ob[(size_t)q*DM + 32 + lo] = f2bf(o1[r]*inv);
  }
}

// ---------------- launcher ----------------
extern "C" void kernel_launch(void* const* d_in, const int* in_sizes, int n_in,
                              void* d_out, int out_size, void* d_ws, size_t ws_size,
                              hipStream_t stream){
  const float* queries = (const float*)d_in[0];
  const float* keys    = (const float*)d_in[1];
  const float* values  = (const float*)d_in[2];
  const float* attw    = (const float*)d_in[3];
  const float* Wq = (const float*)d_in[4];
  const float* bq = (const float*)d_in[5];
  const float* Wk = (const float*)d_in[6];
  const float* bk = (const float*)d_in[7];
  const float* Wv = (const float*)d_in[8];
  const float* bv = (const float*)d_in[9];
  const float* Wo = (const float*)d_in[10];
  const float* bo = (const float*)d_in[11];
  char* ws = (char*)d_ws;
  u16* abf   = (u16*)(ws + OFF_ABF);
  u16* btqkv = (u16*)(ws + OFF_BTQKV);
  u16* bto   = (u16*)(ws + OFF_BTO);
  u16* qp    = (u16*)(ws + OFF_QP);
  u16* kp    = (u16*)(ws + OFF_KP);
  u16* vt    = (u16*)(ws + OFF_VT);
  u16* aout  = (u16*)(ws + OFF_AOUT);
  float* out = (float*)d_out;

  cast3_kernel<<<12288, 256, 0, stream>>>(queries, keys, values, abf);
  twcast_kernel<<<dim3(32,32,4), dim3(32,8), 0, stream>>>(Wq,Wk,Wv,Wo,btqkv,bto);
  gemm0_kernel<<<dim3(24,32), 256, 0, stream>>>(abf, btqkv, bq,bk,bv, qp,kp,vt);
  attn_kernel<<<512, 256, 0, stream>>>(qp, kp, vt, attw, aout);
  gemm1_kernel<<<dim3(8,64), 256, 0, stream>>>(aout, bto, bo, out);
}

// Round 6
// 225.283 us; speedup vs baseline: 2.0603x; 1.0570x over previous
//
#include <hip/hip_runtime.h>
#include <hip/hip_bf16.h>
#include <cstdint>
#include <cstddef>

typedef float f32x16 __attribute__((ext_vector_type(16)));
typedef float f32x4  __attribute__((ext_vector_type(4)));
typedef float f32x2  __attribute__((ext_vector_type(2)));
typedef float f32x4v __attribute__((ext_vector_type(4)));
typedef short short8 __attribute__((ext_vector_type(8)));
typedef unsigned short us4 __attribute__((ext_vector_type(4)));
typedef unsigned int u32;
typedef unsigned short u16;

#define MFMA32(a,b,c) __builtin_amdgcn_mfma_f32_32x32x16_bf16(a,b,c,0,0,0)
#define MFMA16(a,b,c) __builtin_amdgcn_mfma_f32_16x16x32_bf16(a,b,c,0,0,0)

#define HN 16
#define NQL 2048
#define NKL 2048
#define DM 1024

// 0.125 (1/sqrt(64)) * log2(e), folded into Q at projection time.
#define QSCALE 0.18033688011112042f

static __device__ __forceinline__ u16 f2bf(float f){
  union{float f;u32 u;}x; x.f=f; u32 u=x.u;
  return (u16)((u + 0x7fffu + ((u>>16)&1u))>>16);
}

#define AS1q __attribute__((address_space(1)))
#define AS3q __attribute__((address_space(3)))
static __device__ __forceinline__ void gload16(const void* g, void* l){
  __builtin_amdgcn_global_load_lds((const AS1q u32*)g, (AS3q u32*)l, 16, 0, 0);
}
// NT variant: CPol bit1 = NT on gfx940+ -> W stream is evict-first in L2,
// so it stops thrashing the K/V working set. Cache-policy only; semantics equal.
static __device__ __forceinline__ void gload16nt(const void* g, void* l){
  __builtin_amdgcn_global_load_lds((const AS1q u32*)g, (AS3q u32*)l, 16, 0, 2);
}

// ---------------- ws layout (bytes) ----------------
#define OFF_ABF   (size_t)(0)          // 3 * 4096*1024 bf16 = 25165824
#define OFF_BTQKV (size_t)(25165824)   // 3072*1024 bf16 = 6291456
#define OFF_BTO   (size_t)(31457280)   // 1024*1024 bf16 = 2097152
#define OFF_QP    (size_t)(33554432)   // [B,H,2048,64] bf16 = 8388608
#define OFF_KP    (size_t)(41943040)
#define OFF_VT    (size_t)(58720256)   // [B,H,64,2048] bf16
#define OFF_AOUT  (size_t)(67108864)   // [B,2048,1024] bf16
// total 75497472 bytes (72 MB)

// ---------------- cast queries/keys/values -> bf16 ----------------
__global__ void cast3_kernel(const float* __restrict__ q, const float* __restrict__ k,
                             const float* __restrict__ v, u16* __restrict__ dst){
  int i = blockIdx.x*256 + threadIdx.x;              // 3*2^20 float4 units
  const float* src = (i < 1048576) ? q : (i < 2097152 ? k : v);
  int j = i & 1048575;
  f32x4v val = __builtin_nontemporal_load((const f32x4v*)src + j);
  ushort4 o; o.x=f2bf(val.x); o.y=f2bf(val.y); o.z=f2bf(val.z); o.w=f2bf(val.w);
  ((ushort4*)dst)[i] = o;
}

// ---------------- transpose+cast weight matrices ----------------
__global__ void twcast_kernel(const float* __restrict__ wq, const float* __restrict__ wk,
                              const float* __restrict__ wv, const float* __restrict__ wo,
                              u16* __restrict__ btqkv, u16* __restrict__ bto){
  __shared__ float tile[32][33];
  int which = blockIdx.z;
  const float* src = which==0?wq:which==1?wk:which==2?wv:wo;
  u16* dst = which<3 ? btqkv + (size_t)which*1024*1024 : bto;
  int n0 = blockIdx.x*32, k0 = blockIdx.y*32;
  int tx = threadIdx.x, ty = threadIdx.y;
  #pragma unroll
  for (int j=0;j<4;j++)
    tile[ty+8*j][tx] = __builtin_nontemporal_load(&src[(size_t)(k0+ty+8*j)*1024 + n0+tx]);
  __syncthreads();
  #pragma unroll
  for (int j=0;j<4;j++) dst[(size_t)(n0+ty+8*j)*1024 + k0+tx] = f2bf(tile[tx][ty+8*j]);
}

// ---------------- GEMM0: QKV projection (A 4096x1024 * Bt^T), scatter ----------------
// which=0 -> qp (bias+QSCALE), which=1 -> kp (bias), which=2 -> vt TRANSPOSED (bias)
__global__ __launch_bounds__(256) void gemm0_kernel(
    const u16* __restrict__ Abase, const u16* __restrict__ Bt,
    const float* __restrict__ b0, const float* __restrict__ b1, const float* __restrict__ b2,
    u16* __restrict__ qp, u16* __restrict__ kp, u16* __restrict__ vt)
{
  __shared__ u16 lds[2*128*64];   // A tile [128][64], B tile [128][64], 32 KB
  const int t = threadIdx.x;
  const int lane = t & 63, w = t >> 6;
  const int l15 = lane & 15, l4 = lane >> 4;
  const int n0 = blockIdx.x*128, m0 = blockIdx.y*128;
  const int which = n0 >> 10;
  const u16* A = Abase + (size_t)which*4096*1024;
  const int wr = w >> 1, wc = w & 1;

  f32x4 acc[4][4];
  #pragma unroll
  for (int i=0;i<4;i++)
    #pragma unroll
    for (int j=0;j<4;j++){ acc[i][j][0]=0.f; acc[i][j][1]=0.f; acc[i][j][2]=0.f; acc[i][j][3]=0.f; }

  for (int kk=0; kk<16; kk++){
    #pragma unroll
    for (int i=0;i<4;i++){
      int o = i*4096 + w*1024 + lane*16;
      int row = o >> 7, c16 = (o >> 4) & 7;
      int c16s = c16 ^ (row & 7);
      gload16(A + ((size_t)(m0+row)*1024 + kk*64 + c16s*8), (char*)lds + (i*4096 + w*1024));
    }
    #pragma unroll
    for (int i=0;i<4;i++){
      int o = i*4096 + w*1024 + lane*16;
      int row = o >> 7, c16 = (o >> 4) & 7;
      int c16s = c16 ^ (row & 7);
      gload16(Bt + ((size_t)(n0+row)*1024 + kk*64 + c16s*8), (char*)lds + 16384 + (i*4096 + w*1024));
    }
    __syncthreads();

    short8 af[4][2], bf[4][2];
    #pragma unroll
    for (int mr=0;mr<4;mr++)
      #pragma unroll
      for (int ks=0;ks<2;ks++){
        int row = wr*64 + mr*16 + l15;
        int c16 = ks*4 + l4;
        af[mr][ks] = *(const short8*)((const char*)lds + row*128 + ((c16 ^ (row&7))*16));
      }
    #pragma unroll
    for (int nc=0;nc<4;nc++)
      #pragma unroll
      for (int ks=0;ks<2;ks++){
        int row = wc*64 + nc*16 + l15;
        int c16 = ks*4 + l4;
        bf[nc][ks] = *(const short8*)((const char*)lds + 16384 + row*128 + ((c16 ^ (row&7))*16));
      }
    #pragma unroll
    for (int ks=0;ks<2;ks++)
      #pragma unroll
      for (int mr=0;mr<4;mr++)
        #pragma unroll
        for (int nc=0;nc<4;nc++)
          acc[mr][nc] = MFMA16(af[mr][ks], bf[nc][ks], acc[mr][nc]);
    __syncthreads();
  }

  if (which < 2){
    const float* bias = which==0?b0:b1;
    u16* dst = which==0?qp:kp;
    const float sc = (which==0) ? QSCALE : 1.0f;
    #pragma unroll
    for (int mr=0;mr<4;mr++)
      #pragma unroll
      for (int nc=0;nc<4;nc++)
        #pragma unroll
        for (int r=0;r<4;r++){
          int grow = m0 + wr*64 + mr*16 + l4*4 + r;
          int gcol = n0 + wc*64 + nc*16 + l15;
          int c1024 = gcol & 1023;
          float val = (acc[mr][nc][r] + bias[c1024]) * sc;
          int bsel = grow >> 11, nn = grow & 2047;
          int hh = c1024 >> 6, dd = gcol & 63;
          dst[((size_t)(bsel*HN+hh)*NQL + nn)*64 + dd] = f2bf(val);
        }
  } else {
    // V: write transposed directly -> vt[b*16+h][d][n], 4 consecutive n per lane
    #pragma unroll
    for (int mr=0;mr<4;mr++)
      #pragma unroll
      for (int nc=0;nc<4;nc++){
        int grow0 = m0 + wr*64 + mr*16 + l4*4;
        int gcol = n0 + wc*64 + nc*16 + l15;
        int c1024 = gcol & 1023;
        int bsel = grow0 >> 11, nn = grow0 & 2047;
        int hh = c1024 >> 6, dd = c1024 & 63;
        float bv_ = b2[c1024];
        us4 pk;
        pk.x = f2bf(acc[mr][nc][0] + bv_);
        pk.y = f2bf(acc[mr][nc][1] + bv_);
        pk.z = f2bf(acc[mr][nc][2] + bv_);
        pk.w = f2bf(acc[mr][nc][3] + bv_);
        *(us4*)(vt + ((size_t)(bsel*HN+hh)*64 + dd)*NKL + nn) = pk;
      }
  }
}

// ---------------- GEMM1: out = aout(4096x1024 bf16) @ bto^T + bo, f32 out ----------------
__global__ __launch_bounds__(256) void gemm1_kernel(
    const u16* __restrict__ A, const u16* __restrict__ Bt,
    const float* __restrict__ bo, float* __restrict__ out)
{
  __shared__ u16 lds[(64+128)*64];   // A [64][64] @0, B [128][64] @8KB; 24 KB
  const int t = threadIdx.x;
  const int lane = t & 63, w = t >> 6;
  const int l15 = lane & 15, l4 = lane >> 4;
  const int n0 = blockIdx.x*128, m0 = blockIdx.y*64;
  const int wr = w >> 1, wc = w & 1;

  f32x4 acc[2][4];
  #pragma unroll
  for (int i=0;i<2;i++)
    #pragma unroll
    for (int j=0;j<4;j++){ acc[i][j][0]=0.f; acc[i][j][1]=0.f; acc[i][j][2]=0.f; acc[i][j][3]=0.f; }

  for (int kk=0; kk<16; kk++){
    #pragma unroll
    for (int i=0;i<2;i++){
      int o = i*4096 + w*1024 + lane*16;
      int row = o >> 7, c16 = (o >> 4) & 7;
      int c16s = c16 ^ (row & 7);
      gload16(A + ((size_t)(m0+row)*1024 + kk*64 + c16s*8), (char*)lds + (i*4096 + w*1024));
    }
    #pragma unroll
    for (int i=0;i<4;i++){
      int o = i*4096 + w*1024 + lane*16;
      int row = o >> 7, c16 = (o >> 4) & 7;
      int c16s = c16 ^ (row & 7);
      gload16(Bt + ((size_t)(n0+row)*1024 + kk*64 + c16s*8), (char*)lds + 8192 + (i*4096 + w*1024));
    }
    __syncthreads();

    short8 af[2][2], bf[4][2];
    #pragma unroll
    for (int mr=0;mr<2;mr++)
      #pragma unroll
      for (int ks=0;ks<2;ks++){
        int row = wr*32 + mr*16 + l15;
        int c16 = ks*4 + l4;
        af[mr][ks] = *(const short8*)((const char*)lds + row*128 + ((c16 ^ (row&7))*16));
      }
    #pragma unroll
    for (int nc=0;nc<4;nc++)
      #pragma unroll
      for (int ks=0;ks<2;ks++){
        int row = wc*64 + nc*16 + l15;
        int c16 = ks*4 + l4;
        bf[nc][ks] = *(const short8*)((const char*)lds + 8192 + row*128 + ((c16 ^ (row&7))*16));
      }
    #pragma unroll
    for (int ks=0;ks<2;ks++)
      #pragma unroll
      for (int mr=0;mr<2;mr++)
        #pragma unroll
        for (int nc=0;nc<4;nc++)
          acc[mr][nc] = MFMA16(af[mr][ks], bf[nc][ks], acc[mr][nc]);
    __syncthreads();
  }

  #pragma unroll
  for (int mr=0;mr<2;mr++)
    #pragma unroll
    for (int nc=0;nc<4;nc++)
      #pragma unroll
      for (int r=0;r<4;r++){
        int grow = m0 + wr*32 + mr*16 + l4*4 + r;
        int gcol = n0 + wc*64 + nc*16 + l15;
        out[(size_t)grow*1024 + gcol] = acc[mr][nc][r] + bo[gcol];
      }
}

// ---------------- flash attention v3b: NT W stream, early K/V prefetch ----------------
// Block = 4 q-tiles (128 q rows) of one head. K/V double-buffered swizzled LDS
// (shared, global_load_lds, allocating). W per-wave LDS slab, NT (evict-first)
// so the 536 MB W stream doesn't evict the XCD's 2 MB K/V working set.
__global__ __launch_bounds__(256) void attn_kernel(
  const u16* __restrict__ qp, const u16* __restrict__ kp, const u16* __restrict__ vt,
  const float* __restrict__ wts, u16* __restrict__ aout)
{
  __shared__ __align__(16) char lds[81920];
  char* kl = lds;
  char* vl = lds + 16384;
  const int tid = threadIdx.x;
  const int lane = tid & 63, wid = tid >> 6;
  const int lo = lane & 31, hi = lane >> 5;
  char* wl = lds + 32768 + wid*8192;
  char* pl = lds + 65536 + wid*4096;

  // XCD swizzle: XCD (g&7) owns heads [4x, 4x+4) -> ~2MB K/V per XCD L2
  const int g = blockIdx.x;
  const int j = g >> 3;
  const int bh = (g & 7)*4 + (j >> 4);
  const int qblk = j & 15;
  const int b = bh >> 4;
  const int q0 = qblk*128 + wid*32;

  const u16* qb = qp + ((size_t)bh*NQL + q0)*64;
  const u16* kb = kp + (size_t)bh*NKL*64;
  const u16* vb = vt + (size_t)bh*64*NKL;
  const float* wb = wts + ((size_t)bh*NQL + q0)*(size_t)NKL;

  // Q fragments (A-operand): row q = lo, d-slice ks*16 + hi*8
  short8 qf[4];
  #pragma unroll
  for (int ks=0;ks<4;ks++)
    qf[ks] = *(const short8*)(qb + (size_t)lo*64 + ks*16 + hi*8);

  f32x16 o0, o1;
  float ls[16];
  #pragma unroll
  for (int r=0;r<16;r++){ o0[r]=0.f; o1[r]=0.f; ls[r]=0.f; }

  const int le8 = lane & 7, ld8 = lane >> 3;      // for K/V staging
  const int le16 = lane & 15, ld16 = lane >> 4;   // for W staging

  // ---- prologue: stage tile 0 ----
  {
    #pragma unroll
    for (int s=0;s<2;s++){
      int i = wid*2 + s;
      int row = 8*i + ld8;
      int slot = le8 ^ ((row>>1)&7);
      gload16(kb + (size_t)row*64 + slot*8, kl + i*1024);
      int dslot = le8 ^ (ld8&7);
      gload16(vb + (size_t)row*NKL + dslot*8, vl + i*1024);
    }
    #pragma unroll
    for (int i=0;i<8;i++){
      int q = 4*i + ld16;
      gload16nt(wb + (size_t)q*NKL + le16*4, wl + i*1024);
    }
  }
  __syncthreads();

  for (int kt=0; kt<32; kt++){
    const int cur = (kt&1)*8192;
    const int nxt = cur ^ 8192;
    const int kb0 = kt*64;

    // K/V prefetch first: targets nxt buffer (no slab conflict), earliest issue
    if (kt < 31){
      int kb1 = kb0 + 64;
      #pragma unroll
      for (int s=0;s<2;s++){
        int i = wid*2 + s;
        int row = 8*i + ld8;
        int slot = le8 ^ ((row>>1)&7);
        gload16(kb + (size_t)(kb1+row)*64 + slot*8, kl + nxt + i*1024);
        int dslot = le8 ^ (ld8&7);
        gload16(vb + (size_t)row*NKL + kb1 + dslot*8, vl + nxt + i*1024);
      }
    }

    // W[cur] -> regs (per-wave slab; must drain before overwrite-prefetch)
    f32x2 wp[16];
    #pragma unroll
    for (int r=0;r<16;r++){
      int qr = (r&3) + 8*(r>>2) + 4*hi;
      wp[r] = *(const f32x2*)(wl + qr*256 + lo*8);
    }
    // K fragments from swizzled LDS: rows 2lo (kf0), 2lo+1 (kf1)
    short8 kf0[4], kf1[4];
    #pragma unroll
    for (int ks=0;ks<4;ks++){
      int slot = (ks*2 + hi) ^ (lo&7);
      kf0[ks] = *(const short8*)(kl + cur + (2*lo)*128 + slot*16);
      kf1[ks] = *(const short8*)(kl + cur + (2*lo)*128 + 128 + slot*16);
    }
    asm volatile("s_waitcnt lgkmcnt(0)" ::: "memory");
    __builtin_amdgcn_sched_barrier(0);

    // W prefetch (overwrites slab just read) - NT stream
    if (kt < 31){
      int kb1 = kb0 + 64;
      #pragma unroll
      for (int i=0;i<8;i++){
        int q = 4*i + ld16;
        gload16nt(wb + (size_t)q*NKL + kb1 + le16*4, wl + i*1024);
      }
    }

    // QK^T
    f32x16 s0, s1;
    #pragma unroll
    for (int r=0;r<16;r++){ s0[r]=0.f; s1[r]=0.f; }
    #pragma unroll
    for (int ks=0;ks<4;ks++){
      s0 = MFMA32(qf[ks], kf0[ks], s0);
      s1 = MFMA32(qf[ks], kf1[ks], s1);
    }

    // V fragments from swizzled LDS: rows d=lo (vf0), d=32+lo (vf1)
    short8 vf0[4], vf1[4];
    #pragma unroll
    for (int t=0;t<4;t++){
      int slot = (t*2 + hi) ^ (lo&7);
      vf0[t] = *(const short8*)(vl + cur + lo*128 + slot*16);
      vf1[t] = *(const short8*)(vl + cur + (32+lo)*128 + slot*16);
    }

    // flat softmax: p = exp2(s*w); pack to bf16 P tile (swizzled)
    #pragma unroll
    for (int r=0;r<16;r++){
      float p0 = exp2f(s0[r] * wp[r].x);
      float p1 = exp2f(s1[r] * wp[r].y);
      ls[r] += p0 + p1;
      u32 pk;
      asm("v_cvt_pk_bf16_f32 %0, %1, %2" : "=v"(pk) : "v"(p0), "v"(p1));
      int row = (r&3) + 8*(r>>2) + 4*hi;
      *(u32*)(pl + row*128 + ((lo*4) ^ ((row&7)<<4))) = pk;
    }
    asm volatile("s_waitcnt lgkmcnt(0)" ::: "memory");
    // P fragments (A-operand): row q = lo
    short8 pf[4];
    #pragma unroll
    for (int t=0;t<4;t++)
      pf[t] = *(const short8*)(pl + lo*128 + ((t*32 + hi*16) ^ ((lo&7)<<4)));
    #pragma unroll
    for (int t=0;t<4;t++){
      o0 = MFMA32(pf[t], vf0[t], o0);
      o1 = MFMA32(pf[t], vf1[t], o1);
    }
    __syncthreads();   // drains vmcnt (staged tiles) + barrier
  }

  // epilogue: rowsum reduce, divide, store bf16
  u16* ob = aout + ((size_t)b*NQL + q0)*DM + (bh & 15)*64;
  #pragma unroll
  for (int r=0;r<16;r++){
    float L = ls[r];
    L += __shfl_xor(L,1); L += __shfl_xor(L,2); L += __shfl_xor(L,4);
    L += __shfl_xor(L,8); L += __shfl_xor(L,16);
    float inv = 1.0f / L;
    int q = (r&3) + 8*(r>>2) + 4*hi;
    ob[(size_t)q*DM + lo]      = f2bf(o0[r]*inv);
    ob[(size_t)q*DM + 32 + lo] = f2bf(o1[r]*inv);
  }
}

// ---------------- launcher ----------------
extern "C" void kernel_launch(void* const* d_in, const int* in_sizes, int n_in,
                              void* d_out, int out_size, void* d_ws, size_t ws_size,
                              hipStream_t stream){
  const float* queries = (const float*)d_in[0];
  const float* keys    = (const float*)d_in[1];
  const float* values  = (const float*)d_in[2];
  const float* attw    = (const float*)d_in[3];
  const float* Wq = (const float*)d_in[4];
  const float* bq = (const float*)d_in[5];
  const float* Wk = (const float*)d_in[6];
  const float* bk = (const float*)d_in[7];
  const float* Wv = (const float*)d_in[8];
  const float* bv = (const float*)d_in[9];
  const float* Wo = (const float*)d_in[10];
  const float* bo = (const float*)d_in[11];
  char* ws = (char*)d_ws;
  u16* abf   = (u16*)(ws + OFF_ABF);
  u16* btqkv = (u16*)(ws + OFF_BTQKV);
  u16* bto   = (u16*)(ws + OFF_BTO);
  u16* qp    = (u16*)(ws + OFF_QP);
  u16* kp    = (u16*)(ws + OFF_KP);
  u16* vt    = (u16*)(ws + OFF_VT);
  u16* aout  = (u16*)(ws + OFF_AOUT);
  float* out = (float*)d_out;

  cast3_kernel<<<12288, 256, 0, stream>>>(queries, keys, values, abf);
  twcast_kernel<<<dim3(32,32,4), dim3(32,8), 0, stream>>>(Wq,Wk,Wv,Wo,btqkv,bto);
  gemm0_kernel<<<dim3(24,32), 256, 0, stream>>>(abf, btqkv, bq,bk,bv, qp,kp,vt);
  attn_kernel<<<512, 256, 0, stream>>>(qp, kp, vt, attw, aout);
  gemm1_kernel<<<dim3(8,64), 256, 0, stream>>>(aout, bto, bo, out);
}

// Round 7
// 225.112 us; speedup vs baseline: 2.0618x; 1.0008x over previous
//
#include <hip/hip_runtime.h>
#include <hip/hip_bf16.h>
#include <cstdint>
#include <cstddef>

typedef float f32x16 __attribute__((ext_vector_type(16)));
typedef float f32x4  __attribute__((ext_vector_type(4)));
typedef float f32x2  __attribute__((ext_vector_type(2)));
typedef float f32x4v __attribute__((ext_vector_type(4)));
typedef short short8 __attribute__((ext_vector_type(8)));
typedef unsigned short us4 __attribute__((ext_vector_type(4)));
typedef unsigned int u32;
typedef unsigned short u16;

#define MFMA32(a,b,c) __builtin_amdgcn_mfma_f32_32x32x16_bf16(a,b,c,0,0,0)
#define MFMA16(a,b,c) __builtin_amdgcn_mfma_f32_16x16x32_bf16(a,b,c,0,0,0)

#define HN 16
#define NQL 2048
#define NKL 2048
#define DM 1024

// 0.125 (1/sqrt(64)) * log2(e), folded into Q at projection time.
#define QSCALE 0.18033688011112042f

static __device__ __forceinline__ u16 f2bf(float f){
  union{float f;u32 u;}x; x.f=f; u32 u=x.u;
  return (u16)((u + 0x7fffu + ((u>>16)&1u))>>16);
}

#define AS1q __attribute__((address_space(1)))
#define AS3q __attribute__((address_space(3)))
static __device__ __forceinline__ void gload16(const void* g, void* l){
  __builtin_amdgcn_global_load_lds((const AS1q u32*)g, (AS3q u32*)l, 16, 0, 0);
}
// W-stream variant: CPol NT|SC1 (0x12). On MI300-series CPol, SC1 on a load =
// system-scope = L2 BYPASS; NT = evict-first fallback. Goal: the 536 MB W
// stream causes zero L2 pollution so the 2 MB/XCD K/V working set stays
// L2-resident. Cache-policy only -> no semantic change.
static __device__ __forceinline__ void gload16nt(const void* g, void* l){
  __builtin_amdgcn_global_load_lds((const AS1q u32*)g, (AS3q u32*)l, 16, 0, 0x12);
}

// ---------------- ws layout (bytes) ----------------
#define OFF_ABF   (size_t)(0)          // 3 * 4096*1024 bf16 = 25165824
#define OFF_BTQKV (size_t)(25165824)   // 3072*1024 bf16 = 6291456
#define OFF_BTO   (size_t)(31457280)   // 1024*1024 bf16 = 2097152
#define OFF_QP    (size_t)(33554432)   // [B,H,2048,64] bf16 = 8388608
#define OFF_KP    (size_t)(41943040)
#define OFF_VT    (size_t)(58720256)   // [B,H,64,2048] bf16
#define OFF_AOUT  (size_t)(67108864)   // [B,2048,1024] bf16
// total 75497472 bytes (72 MB)

// ---------------- cast queries/keys/values -> bf16 ----------------
__global__ void cast3_kernel(const float* __restrict__ q, const float* __restrict__ k,
                             const float* __restrict__ v, u16* __restrict__ dst){
  int i = blockIdx.x*256 + threadIdx.x;              // 3*2^20 float4 units
  const float* src = (i < 1048576) ? q : (i < 2097152 ? k : v);
  int j = i & 1048575;
  f32x4v val = __builtin_nontemporal_load((const f32x4v*)src + j);
  ushort4 o; o.x=f2bf(val.x); o.y=f2bf(val.y); o.z=f2bf(val.z); o.w=f2bf(val.w);
  ((ushort4*)dst)[i] = o;
}

// ---------------- transpose+cast weight matrices ----------------
__global__ void twcast_kernel(const float* __restrict__ wq, const float* __restrict__ wk,
                              const float* __restrict__ wv, const float* __restrict__ wo,
                              u16* __restrict__ btqkv, u16* __restrict__ bto){
  __shared__ float tile[32][33];
  int which = blockIdx.z;
  const float* src = which==0?wq:which==1?wk:which==2?wv:wo;
  u16* dst = which<3 ? btqkv + (size_t)which*1024*1024 : bto;
  int n0 = blockIdx.x*32, k0 = blockIdx.y*32;
  int tx = threadIdx.x, ty = threadIdx.y;
  #pragma unroll
  for (int j=0;j<4;j++)
    tile[ty+8*j][tx] = __builtin_nontemporal_load(&src[(size_t)(k0+ty+8*j)*1024 + n0+tx]);
  __syncthreads();
  #pragma unroll
  for (int j=0;j<4;j++) dst[(size_t)(n0+ty+8*j)*1024 + k0+tx] = f2bf(tile[tx][ty+8*j]);
}

// ---------------- GEMM0: QKV projection (A 4096x1024 * Bt^T), scatter ----------------
// which=0 -> qp (bias+QSCALE), which=1 -> kp (bias), which=2 -> vt TRANSPOSED (bias)
__global__ __launch_bounds__(256) void gemm0_kernel(
    const u16* __restrict__ Abase, const u16* __restrict__ Bt,
    const float* __restrict__ b0, const float* __restrict__ b1, const float* __restrict__ b2,
    u16* __restrict__ qp, u16* __restrict__ kp, u16* __restrict__ vt)
{
  __shared__ u16 lds[2*128*64];   // A tile [128][64], B tile [128][64], 32 KB
  const int t = threadIdx.x;
  const int lane = t & 63, w = t >> 6;
  const int l15 = lane & 15, l4 = lane >> 4;
  const int n0 = blockIdx.x*128, m0 = blockIdx.y*128;
  const int which = n0 >> 10;
  const u16* A = Abase + (size_t)which*4096*1024;
  const int wr = w >> 1, wc = w & 1;

  f32x4 acc[4][4];
  #pragma unroll
  for (int i=0;i<4;i++)
    #pragma unroll
    for (int j=0;j<4;j++){ acc[i][j][0]=0.f; acc[i][j][1]=0.f; acc[i][j][2]=0.f; acc[i][j][3]=0.f; }

  for (int kk=0; kk<16; kk++){
    #pragma unroll
    for (int i=0;i<4;i++){
      int o = i*4096 + w*1024 + lane*16;
      int row = o >> 7, c16 = (o >> 4) & 7;
      int c16s = c16 ^ (row & 7);
      gload16(A + ((size_t)(m0+row)*1024 + kk*64 + c16s*8), (char*)lds + (i*4096 + w*1024));
    }
    #pragma unroll
    for (int i=0;i<4;i++){
      int o = i*4096 + w*1024 + lane*16;
      int row = o >> 7, c16 = (o >> 4) & 7;
      int c16s = c16 ^ (row & 7);
      gload16(Bt + ((size_t)(n0+row)*1024 + kk*64 + c16s*8), (char*)lds + 16384 + (i*4096 + w*1024));
    }
    __syncthreads();

    short8 af[4][2], bf[4][2];
    #pragma unroll
    for (int mr=0;mr<4;mr++)
      #pragma unroll
      for (int ks=0;ks<2;ks++){
        int row = wr*64 + mr*16 + l15;
        int c16 = ks*4 + l4;
        af[mr][ks] = *(const short8*)((const char*)lds + row*128 + ((c16 ^ (row&7))*16));
      }
    #pragma unroll
    for (int nc=0;nc<4;nc++)
      #pragma unroll
      for (int ks=0;ks<2;ks++){
        int row = wc*64 + nc*16 + l15;
        int c16 = ks*4 + l4;
        bf[nc][ks] = *(const short8*)((const char*)lds + 16384 + row*128 + ((c16 ^ (row&7))*16));
      }
    #pragma unroll
    for (int ks=0;ks<2;ks++)
      #pragma unroll
      for (int mr=0;mr<4;mr++)
        #pragma unroll
        for (int nc=0;nc<4;nc++)
          acc[mr][nc] = MFMA16(af[mr][ks], bf[nc][ks], acc[mr][nc]);
    __syncthreads();
  }

  if (which < 2){
    const float* bias = which==0?b0:b1;
    u16* dst = which==0?qp:kp;
    const float sc = (which==0) ? QSCALE : 1.0f;
    #pragma unroll
    for (int mr=0;mr<4;mr++)
      #pragma unroll
      for (int nc=0;nc<4;nc++)
        #pragma unroll
        for (int r=0;r<4;r++){
          int grow = m0 + wr*64 + mr*16 + l4*4 + r;
          int gcol = n0 + wc*64 + nc*16 + l15;
          int c1024 = gcol & 1023;
          float val = (acc[mr][nc][r] + bias[c1024]) * sc;
          int bsel = grow >> 11, nn = grow & 2047;
          int hh = c1024 >> 6, dd = gcol & 63;
          dst[((size_t)(bsel*HN+hh)*NQL + nn)*64 + dd] = f2bf(val);
        }
  } else {
    // V: write transposed directly -> vt[b*16+h][d][n], 4 consecutive n per lane
    #pragma unroll
    for (int mr=0;mr<4;mr++)
      #pragma unroll
      for (int nc=0;nc<4;nc++){
        int grow0 = m0 + wr*64 + mr*16 + l4*4;
        int gcol = n0 + wc*64 + nc*16 + l15;
        int c1024 = gcol & 1023;
        int bsel = grow0 >> 11, nn = grow0 & 2047;
        int hh = c1024 >> 6, dd = c1024 & 63;
        float bv_ = b2[c1024];
        us4 pk;
        pk.x = f2bf(acc[mr][nc][0] + bv_);
        pk.y = f2bf(acc[mr][nc][1] + bv_);
        pk.z = f2bf(acc[mr][nc][2] + bv_);
        pk.w = f2bf(acc[mr][nc][3] + bv_);
        *(us4*)(vt + ((size_t)(bsel*HN+hh)*64 + dd)*NKL + nn) = pk;
      }
  }
}

// ---------------- GEMM1: out = aout(4096x1024 bf16) @ bto^T + bo, f32 out ----------------
__global__ __launch_bounds__(256) void gemm1_kernel(
    const u16* __restrict__ A, const u16* __restrict__ Bt,
    const float* __restrict__ bo, float* __restrict__ out)
{
  __shared__ u16 lds[(64+128)*64];   // A [64][64] @0, B [128][64] @8KB; 24 KB
  const int t = threadIdx.x;
  const int lane = t & 63, w = t >> 6;
  const int l15 = lane & 15, l4 = lane >> 4;
  const int n0 = blockIdx.x*128, m0 = blockIdx.y*64;
  const int wr = w >> 1, wc = w & 1;

  f32x4 acc[2][4];
  #pragma unroll
  for (int i=0;i<2;i++)
    #pragma unroll
    for (int j=0;j<4;j++){ acc[i][j][0]=0.f; acc[i][j][1]=0.f; acc[i][j][2]=0.f; acc[i][j][3]=0.f; }

  for (int kk=0; kk<16; kk++){
    #pragma unroll
    for (int i=0;i<2;i++){
      int o = i*4096 + w*1024 + lane*16;
      int row = o >> 7, c16 = (o >> 4) & 7;
      int c16s = c16 ^ (row & 7);
      gload16(A + ((size_t)(m0+row)*1024 + kk*64 + c16s*8), (char*)lds + (i*4096 + w*1024));
    }
    #pragma unroll
    for (int i=0;i<4;i++){
      int o = i*4096 + w*1024 + lane*16;
      int row = o >> 7, c16 = (o >> 4) & 7;
      int c16s = c16 ^ (row & 7);
      gload16(Bt + ((size_t)(n0+row)*1024 + kk*64 + c16s*8), (char*)lds + 8192 + (i*4096 + w*1024));
    }
    __syncthreads();

    short8 af[2][2], bf[4][2];
    #pragma unroll
    for (int mr=0;mr<2;mr++)
      #pragma unroll
      for (int ks=0;ks<2;ks++){
        int row = wr*32 + mr*16 + l15;
        int c16 = ks*4 + l4;
        af[mr][ks] = *(const short8*)((const char*)lds + row*128 + ((c16 ^ (row&7))*16));
      }
    #pragma unroll
    for (int nc=0;nc<4;nc++)
      #pragma unroll
      for (int ks=0;ks<2;ks++){
        int row = wc*64 + nc*16 + l15;
        int c16 = ks*4 + l4;
        bf[nc][ks] = *(const short8*)((const char*)lds + 8192 + row*128 + ((c16 ^ (row&7))*16));
      }
    #pragma unroll
    for (int ks=0;ks<2;ks++)
      #pragma unroll
      for (int mr=0;mr<2;mr++)
        #pragma unroll
        for (int nc=0;nc<4;nc++)
          acc[mr][nc] = MFMA16(af[mr][ks], bf[nc][ks], acc[mr][nc]);
    __syncthreads();
  }

  #pragma unroll
  for (int mr=0;mr<2;mr++)
    #pragma unroll
    for (int nc=0;nc<4;nc++)
      #pragma unroll
      for (int r=0;r<4;r++){
        int grow = m0 + wr*32 + mr*16 + l4*4 + r;
        int gcol = n0 + wc*64 + nc*16 + l15;
        out[(size_t)grow*1024 + gcol] = acc[mr][nc][r] + bo[gcol];
      }
}

// ---------------- flash attention v3c: W stream bypasses L2 (NT|SC1) ----------------
// Block = 4 q-tiles (128 q rows) of one head. K/V double-buffered swizzled LDS
// (shared, global_load_lds, allocating -> L2-resident). W per-wave LDS slab,
// L2-bypass so the 536 MB stream never evicts the 2 MB/XCD K/V working set.
__global__ __launch_bounds__(256) void attn_kernel(
  const u16* __restrict__ qp, const u16* __restrict__ kp, const u16* __restrict__ vt,
  const float* __restrict__ wts, u16* __restrict__ aout)
{
  __shared__ __align__(16) char lds[81920];
  char* kl = lds;
  char* vl = lds + 16384;
  const int tid = threadIdx.x;
  const int lane = tid & 63, wid = tid >> 6;
  const int lo = lane & 31, hi = lane >> 5;
  char* wl = lds + 32768 + wid*8192;
  char* pl = lds + 65536 + wid*4096;

  // XCD swizzle: XCD (g&7) owns heads [4x, 4x+4) -> ~2MB K/V per XCD L2
  const int g = blockIdx.x;
  const int j = g >> 3;
  const int bh = (g & 7)*4 + (j >> 4);
  const int qblk = j & 15;
  const int b = bh >> 4;
  const int q0 = qblk*128 + wid*32;

  const u16* qb = qp + ((size_t)bh*NQL + q0)*64;
  const u16* kb = kp + (size_t)bh*NKL*64;
  const u16* vb = vt + (size_t)bh*64*NKL;
  const float* wb = wts + ((size_t)bh*NQL + q0)*(size_t)NKL;

  // Q fragments (A-operand): row q = lo, d-slice ks*16 + hi*8
  short8 qf[4];
  #pragma unroll
  for (int ks=0;ks<4;ks++)
    qf[ks] = *(const short8*)(qb + (size_t)lo*64 + ks*16 + hi*8);

  f32x16 o0, o1;
  float ls[16];
  #pragma unroll
  for (int r=0;r<16;r++){ o0[r]=0.f; o1[r]=0.f; ls[r]=0.f; }

  const int le8 = lane & 7, ld8 = lane >> 3;      // for K/V staging
  const int le16 = lane & 15, ld16 = lane >> 4;   // for W staging

  // ---- prologue: stage tile 0 ----
  {
    #pragma unroll
    for (int s=0;s<2;s++){
      int i = wid*2 + s;
      int row = 8*i + ld8;
      int slot = le8 ^ ((row>>1)&7);
      gload16(kb + (size_t)row*64 + slot*8, kl + i*1024);
      int dslot = le8 ^ (ld8&7);
      gload16(vb + (size_t)row*NKL + dslot*8, vl + i*1024);
    }
    #pragma unroll
    for (int i=0;i<8;i++){
      int q = 4*i + ld16;
      gload16nt(wb + (size_t)q*NKL + le16*4, wl + i*1024);
    }
  }
  __syncthreads();

  for (int kt=0; kt<32; kt++){
    const int cur = (kt&1)*8192;
    const int nxt = cur ^ 8192;
    const int kb0 = kt*64;

    // K/V prefetch first: targets nxt buffer (no slab conflict), earliest issue
    if (kt < 31){
      int kb1 = kb0 + 64;
      #pragma unroll
      for (int s=0;s<2;s++){
        int i = wid*2 + s;
        int row = 8*i + ld8;
        int slot = le8 ^ ((row>>1)&7);
        gload16(kb + (size_t)(kb1+row)*64 + slot*8, kl + nxt + i*1024);
        int dslot = le8 ^ (ld8&7);
        gload16(vb + (size_t)row*NKL + kb1 + dslot*8, vl + nxt + i*1024);
      }
    }

    // W[cur] -> regs (per-wave slab; must drain before overwrite-prefetch)
    f32x2 wp[16];
    #pragma unroll
    for (int r=0;r<16;r++){
      int qr = (r&3) + 8*(r>>2) + 4*hi;
      wp[r] = *(const f32x2*)(wl + qr*256 + lo*8);
    }
    // K fragments from swizzled LDS: rows 2lo (kf0), 2lo+1 (kf1)
    short8 kf0[4], kf1[4];
    #pragma unroll
    for (int ks=0;ks<4;ks++){
      int slot = (ks*2 + hi) ^ (lo&7);
      kf0[ks] = *(const short8*)(kl + cur + (2*lo)*128 + slot*16);
      kf1[ks] = *(const short8*)(kl + cur + (2*lo)*128 + 128 + slot*16);
    }
    asm volatile("s_waitcnt lgkmcnt(0)" ::: "memory");
    __builtin_amdgcn_sched_barrier(0);

    // W prefetch (overwrites slab just read) - L2-bypass stream
    if (kt < 31){
      int kb1 = kb0 + 64;
      #pragma unroll
      for (int i=0;i<8;i++){
        int q = 4*i + ld16;
        gload16nt(wb + (size_t)q*NKL + kb1 + le16*4, wl + i*1024);
      }
    }

    // QK^T
    f32x16 s0, s1;
    #pragma unroll
    for (int r=0;r<16;r++){ s0[r]=0.f; s1[r]=0.f; }
    #pragma unroll
    for (int ks=0;ks<4;ks++){
      s0 = MFMA32(qf[ks], kf0[ks], s0);
      s1 = MFMA32(qf[ks], kf1[ks], s1);
    }

    // V fragments from swizzled LDS: rows d=lo (vf0), d=32+lo (vf1)
    short8 vf0[4], vf1[4];
    #pragma unroll
    for (int t=0;t<4;t++){
      int slot = (t*2 + hi) ^ (lo&7);
      vf0[t] = *(const short8*)(vl + cur + lo*128 + slot*16);
      vf1[t] = *(const short8*)(vl + cur + (32+lo)*128 + slot*16);
    }

    // flat softmax: p = exp2(s*w); pack to bf16 P tile (swizzled)
    #pragma unroll
    for (int r=0;r<16;r++){
      float p0 = exp2f(s0[r] * wp[r].x);
      float p1 = exp2f(s1[r] * wp[r].y);
      ls[r] += p0 + p1;
      u32 pk;
      asm("v_cvt_pk_bf16_f32 %0, %1, %2" : "=v"(pk) : "v"(p0), "v"(p1));
      int row = (r&3) + 8*(r>>2) + 4*hi;
      *(u32*)(pl + row*128 + ((lo*4) ^ ((row&7)<<4))) = pk;
    }
    asm volatile("s_waitcnt lgkmcnt(0)" ::: "memory");
    // P fragments (A-operand): row q = lo
    short8 pf[4];
    #pragma unroll
    for (int t=0;t<4;t++)
      pf[t] = *(const short8*)(pl + lo*128 + ((t*32 + hi*16) ^ ((lo&7)<<4)));
    #pragma unroll
    for (int t=0;t<4;t++){
      o0 = MFMA32(pf[t], vf0[t], o0);
      o1 = MFMA32(pf[t], vf1[t], o1);
    }
    __syncthreads();   // drains vmcnt (staged tiles) + barrier
  }

  // epilogue: rowsum reduce, divide, store bf16
  u16* ob = aout + ((size_t)b*NQL + q0)*DM + (bh & 15)*64;
  #pragma unroll
  for (int r=0;r<16;r++){
    float L = ls[r];
    L += __shfl_xor(L,1); L += __shfl_xor(L,2); L += __shfl_xor(L,4);
    L += __shfl_xor(L,8); L += __shfl_xor(L,16);
    float inv = 1.0f / L;
    int q = (r&3) + 8*(r>>2) + 4*hi;
    ob[(size_t)q*DM + lo]      = f2bf(o0[r]*inv);
    ob[(size_t)q*DM + 32 + lo] = f2bf(o1[r]*inv);
  }
}

// ---------------- launcher ----------------
extern "C" void kernel_launch(void* const* d_in, const int* in_sizes, int n_in,
                              void* d_out, int out_size, void* d_ws, size_t ws_size,
                              hipStream_t stream){
  const float* queries = (const float*)d_in[0];
  const float* keys    = (const float*)d_in[1];
  const float* values  = (const float*)d_in[2];
  const float* attw    = (const float*)d_in[3];
  const float* Wq = (const float*)d_in[4];
  const float* bq = (const float*)d_in[5];
  const float* Wk = (const float*)d_in[6];
  const float* bk = (const float*)d_in[7];
  const float* Wv = (const float*)d_in[8];
  const float* bv = (const float*)d_in[9];
  const float* Wo = (const float*)d_in[10];
  const float* bo = (const float*)d_in[11];
  char* ws = (char*)d_ws;
  u16* abf   = (u16*)(ws + OFF_ABF);
  u16* btqkv = (u16*)(ws + OFF_BTQKV);
  u16* bto   = (u16*)(ws + OFF_BTO);
  u16* qp    = (u16*)(ws + OFF_QP);
  u16* kp    = (u16*)(ws + OFF_KP);
  u16* vt    = (u16*)(ws + OFF_VT);
  u16* aout  = (u16*)(ws + OFF_AOUT);
  float* out = (float*)d_out;

  cast3_kernel<<<12288, 256, 0, stream>>>(queries, keys, values, abf);
  twcast_kernel<<<dim3(32,32,4), dim3(32,8), 0, stream>>>(Wq,Wk,Wv,Wo,btqkv,bto);
  gemm0_kernel<<<dim3(24,32), 256, 0, stream>>>(abf, btqkv, bq,bk,bv, qp,kp,vt);
  attn_kernel<<<512, 256, 0, stream>>>(qp, kp, vt, attw, aout);
  gemm1_kernel<<<dim3(8,64), 256, 0, stream>>>(aout, bto, bo, out);
}

// Round 8
// 213.535 us; speedup vs baseline: 2.1736x; 1.0542x over previous
//
#include <hip/hip_runtime.h>
#include <hip/hip_bf16.h>
#include <cstdint>
#include <cstddef>

typedef float f32x16 __attribute__((ext_vector_type(16)));
typedef float f32x4  __attribute__((ext_vector_type(4)));
typedef float f32x2  __attribute__((ext_vector_type(2)));
typedef float f32x4v __attribute__((ext_vector_type(4)));
typedef short short8 __attribute__((ext_vector_type(8)));
typedef unsigned short us4 __attribute__((ext_vector_type(4)));
typedef unsigned int u32;
typedef unsigned short u16;

#define MFMA32(a,b,c) __builtin_amdgcn_mfma_f32_32x32x16_bf16(a,b,c,0,0,0)
#define MFMA16(a,b,c) __builtin_amdgcn_mfma_f32_16x16x32_bf16(a,b,c,0,0,0)

#define HN 16
#define NQL 2048
#define NKL 2048
#define DM 1024

// 0.125 (1/sqrt(64)) * log2(e), folded into Q at projection time.
#define QSCALE 0.18033688011112042f

static __device__ __forceinline__ u16 f2bf(float f){
  union{float f;u32 u;}x; x.f=f; u32 u=x.u;
  return (u16)((u + 0x7fffu + ((u>>16)&1u))>>16);
}

#define AS1q __attribute__((address_space(1)))
#define AS3q __attribute__((address_space(3)))
static __device__ __forceinline__ void gload16(const void* g, void* l){
  __builtin_amdgcn_global_load_lds((const AS1q u32*)g, (AS3q u32*)l, 16, 0, 0);
}
// W-stream: NT (evict-first) — best measured policy (R6: -13us; R7 SC1: null).
static __device__ __forceinline__ void gload16nt(const void* g, void* l){
  __builtin_amdgcn_global_load_lds((const AS1q u32*)g, (AS3q u32*)l, 16, 0, 2);
}

// ---------------- ws layout (bytes) ----------------
#define OFF_ABF   (size_t)(0)          // 3 * 4096*1024 bf16 = 25165824
#define OFF_BTQKV (size_t)(25165824)   // 3072*1024 bf16 = 6291456
#define OFF_BTO   (size_t)(31457280)   // 1024*1024 bf16 = 2097152
#define OFF_QP    (size_t)(33554432)   // [B,H,2048,64] bf16 = 8388608
#define OFF_KP    (size_t)(41943040)
#define OFF_VT    (size_t)(58720256)   // [B,H,64,2048] bf16
#define OFF_AOUT  (size_t)(67108864)   // [B,2048,1024] bf16
// total 75497472 bytes (72 MB)

// ---------------- cast queries/keys/values -> bf16 ----------------
__global__ void cast3_kernel(const float* __restrict__ q, const float* __restrict__ k,
                             const float* __restrict__ v, u16* __restrict__ dst){
  int i = blockIdx.x*256 + threadIdx.x;              // 3*2^20 float4 units
  const float* src = (i < 1048576) ? q : (i < 2097152 ? k : v);
  int j = i & 1048575;
  f32x4v val = __builtin_nontemporal_load((const f32x4v*)src + j);
  ushort4 o; o.x=f2bf(val.x); o.y=f2bf(val.y); o.z=f2bf(val.z); o.w=f2bf(val.w);
  ((ushort4*)dst)[i] = o;
}

// ---------------- transpose+cast weight matrices ----------------
__global__ void twcast_kernel(const float* __restrict__ wq, const float* __restrict__ wk,
                              const float* __restrict__ wv, const float* __restrict__ wo,
                              u16* __restrict__ btqkv, u16* __restrict__ bto){
  __shared__ float tile[32][33];
  int which = blockIdx.z;
  const float* src = which==0?wq:which==1?wk:which==2?wv:wo;
  u16* dst = which<3 ? btqkv + (size_t)which*1024*1024 : bto;
  int n0 = blockIdx.x*32, k0 = blockIdx.y*32;
  int tx = threadIdx.x, ty = threadIdx.y;
  #pragma unroll
  for (int j=0;j<4;j++)
    tile[ty+8*j][tx] = __builtin_nontemporal_load(&src[(size_t)(k0+ty+8*j)*1024 + n0+tx]);
  __syncthreads();
  #pragma unroll
  for (int j=0;j<4;j++) dst[(size_t)(n0+ty+8*j)*1024 + k0+tx] = f2bf(tile[tx][ty+8*j]);
}

// ---------------- GEMM0: QKV projection (A 4096x1024 * Bt^T), scatter ----------------
// which=0 -> qp (bias+QSCALE), which=1 -> kp (bias), which=2 -> vt TRANSPOSED (bias)
__global__ __launch_bounds__(256) void gemm0_kernel(
    const u16* __restrict__ Abase, const u16* __restrict__ Bt,
    const float* __restrict__ b0, const float* __restrict__ b1, const float* __restrict__ b2,
    u16* __restrict__ qp, u16* __restrict__ kp, u16* __restrict__ vt)
{
  __shared__ u16 lds[2*128*64];   // A tile [128][64], B tile [128][64], 32 KB
  const int t = threadIdx.x;
  const int lane = t & 63, w = t >> 6;
  const int l15 = lane & 15, l4 = lane >> 4;
  const int n0 = blockIdx.x*128, m0 = blockIdx.y*128;
  const int which = n0 >> 10;
  const u16* A = Abase + (size_t)which*4096*1024;
  const int wr = w >> 1, wc = w & 1;

  f32x4 acc[4][4];
  #pragma unroll
  for (int i=0;i<4;i++)
    #pragma unroll
    for (int j=0;j<4;j++){ acc[i][j][0]=0.f; acc[i][j][1]=0.f; acc[i][j][2]=0.f; acc[i][j][3]=0.f; }

  for (int kk=0; kk<16; kk++){
    #pragma unroll
    for (int i=0;i<4;i++){
      int o = i*4096 + w*1024 + lane*16;
      int row = o >> 7, c16 = (o >> 4) & 7;
      int c16s = c16 ^ (row & 7);
      gload16(A + ((size_t)(m0+row)*1024 + kk*64 + c16s*8), (char*)lds + (i*4096 + w*1024));
    }
    #pragma unroll
    for (int i=0;i<4;i++){
      int o = i*4096 + w*1024 + lane*16;
      int row = o >> 7, c16 = (o >> 4) & 7;
      int c16s = c16 ^ (row & 7);
      gload16(Bt + ((size_t)(n0+row)*1024 + kk*64 + c16s*8), (char*)lds + 16384 + (i*4096 + w*1024));
    }
    __syncthreads();

    short8 af[4][2], bf[4][2];
    #pragma unroll
    for (int mr=0;mr<4;mr++)
      #pragma unroll
      for (int ks=0;ks<2;ks++){
        int row = wr*64 + mr*16 + l15;
        int c16 = ks*4 + l4;
        af[mr][ks] = *(const short8*)((const char*)lds + row*128 + ((c16 ^ (row&7))*16));
      }
    #pragma unroll
    for (int nc=0;nc<4;nc++)
      #pragma unroll
      for (int ks=0;ks<2;ks++){
        int row = wc*64 + nc*16 + l15;
        int c16 = ks*4 + l4;
        bf[nc][ks] = *(const short8*)((const char*)lds + 16384 + row*128 + ((c16 ^ (row&7))*16));
      }
    #pragma unroll
    for (int ks=0;ks<2;ks++)
      #pragma unroll
      for (int mr=0;mr<4;mr++)
        #pragma unroll
        for (int nc=0;nc<4;nc++)
          acc[mr][nc] = MFMA16(af[mr][ks], bf[nc][ks], acc[mr][nc]);
    __syncthreads();
  }

  if (which < 2){
    const float* bias = which==0?b0:b1;
    u16* dst = which==0?qp:kp;
    const float sc = (which==0) ? QSCALE : 1.0f;
    #pragma unroll
    for (int mr=0;mr<4;mr++)
      #pragma unroll
      for (int nc=0;nc<4;nc++)
        #pragma unroll
        for (int r=0;r<4;r++){
          int grow = m0 + wr*64 + mr*16 + l4*4 + r;
          int gcol = n0 + wc*64 + nc*16 + l15;
          int c1024 = gcol & 1023;
          float val = (acc[mr][nc][r] + bias[c1024]) * sc;
          int bsel = grow >> 11, nn = grow & 2047;
          int hh = c1024 >> 6, dd = gcol & 63;
          dst[((size_t)(bsel*HN+hh)*NQL + nn)*64 + dd] = f2bf(val);
        }
  } else {
    // V: write transposed directly -> vt[b*16+h][d][n], 4 consecutive n per lane
    #pragma unroll
    for (int mr=0;mr<4;mr++)
      #pragma unroll
      for (int nc=0;nc<4;nc++){
        int grow0 = m0 + wr*64 + mr*16 + l4*4;
        int gcol = n0 + wc*64 + nc*16 + l15;
        int c1024 = gcol & 1023;
        int bsel = grow0 >> 11, nn = grow0 & 2047;
        int hh = c1024 >> 6, dd = c1024 & 63;
        float bv_ = b2[c1024];
        us4 pk;
        pk.x = f2bf(acc[mr][nc][0] + bv_);
        pk.y = f2bf(acc[mr][nc][1] + bv_);
        pk.z = f2bf(acc[mr][nc][2] + bv_);
        pk.w = f2bf(acc[mr][nc][3] + bv_);
        *(us4*)(vt + ((size_t)(bsel*HN+hh)*64 + dd)*NKL + nn) = pk;
      }
  }
}

// ---------------- GEMM1: out = aout(4096x1024 bf16) @ bto^T + bo, f32 out ----------------
__global__ __launch_bounds__(256) void gemm1_kernel(
    const u16* __restrict__ A, const u16* __restrict__ Bt,
    const float* __restrict__ bo, float* __restrict__ out)
{
  __shared__ u16 lds[(64+128)*64];   // A [64][64] @0, B [128][64] @8KB; 24 KB
  const int t = threadIdx.x;
  const int lane = t & 63, w = t >> 6;
  const int l15 = lane & 15, l4 = lane >> 4;
  const int n0 = blockIdx.x*128, m0 = blockIdx.y*64;
  const int wr = w >> 1, wc = w & 1;

  f32x4 acc[2][4];
  #pragma unroll
  for (int i=0;i<2;i++)
    #pragma unroll
    for (int j=0;j<4;j++){ acc[i][j][0]=0.f; acc[i][j][1]=0.f; acc[i][j][2]=0.f; acc[i][j][3]=0.f; }

  for (int kk=0; kk<16; kk++){
    #pragma unroll
    for (int i=0;i<2;i++){
      int o = i*4096 + w*1024 + lane*16;
      int row = o >> 7, c16 = (o >> 4) & 7;
      int c16s = c16 ^ (row & 7);
      gload16(A + ((size_t)(m0+row)*1024 + kk*64 + c16s*8), (char*)lds + (i*4096 + w*1024));
    }
    #pragma unroll
    for (int i=0;i<4;i++){
      int o = i*4096 + w*1024 + lane*16;
      int row = o >> 7, c16 = (o >> 4) & 7;
      int c16s = c16 ^ (row & 7);
      gload16(Bt + ((size_t)(n0+row)*1024 + kk*64 + c16s*8), (char*)lds + 8192 + (i*4096 + w*1024));
    }
    __syncthreads();

    short8 af[2][2], bf[4][2];
    #pragma unroll
    for (int mr=0;mr<2;mr++)
      #pragma unroll
      for (int ks=0;ks<2;ks++){
        int row = wr*32 + mr*16 + l15;
        int c16 = ks*4 + l4;
        af[mr][ks] = *(const short8*)((const char*)lds + row*128 + ((c16 ^ (row&7))*16));
      }
    #pragma unroll
    for (int nc=0;nc<4;nc++)
      #pragma unroll
      for (int ks=0;ks<2;ks++){
        int row = wc*64 + nc*16 + l15;
        int c16 = ks*4 + l4;
        bf[nc][ks] = *(const short8*)((const char*)lds + 8192 + row*128 + ((c16 ^ (row&7))*16));
      }
    #pragma unroll
    for (int ks=0;ks<2;ks++)
      #pragma unroll
      for (int mr=0;mr<2;mr++)
        #pragma unroll
        for (int nc=0;nc<4;nc++)
          acc[mr][nc] = MFMA16(af[mr][ks], bf[nc][ks], acc[mr][nc]);
    __syncthreads();
  }

  #pragma unroll
  for (int mr=0;mr<2;mr++)
    #pragma unroll
    for (int nc=0;nc<4;nc++)
      #pragma unroll
      for (int r=0;r<4;r++){
        int grow = m0 + wr*32 + mr*16 + l4*4 + r;
        int gcol = n0 + wc*64 + nc*16 + l15;
        out[(size_t)grow*1024 + gcol] = acc[mr][nc][r] + bo[gcol];
      }
}

// ---------------- flash attention v4: 8-wave blocks, 256 q-rows/block ----------------
// Grid 256 = 1 block/CU. Each block: one head, q-rows [qblk*256, +256), 8 waves
// of 32 rows. K/V double-buffered swizzled LDS shared by all 8 waves (halves
// both staging cost/thread and K/V HBM re-read traffic: 16 -> 8 reads of K/V).
// W per-wave 8KB LDS slab (NT stream), flat softmax, n-interleave 2lo/2lo+1.
// LDS: kl 16K | vl 16K | wl 8x8K | pl 8x4K = 128 KB.
__global__ __launch_bounds__(512) void attn_kernel(
  const u16* __restrict__ qp, const u16* __restrict__ kp, const u16* __restrict__ vt,
  const float* __restrict__ wts, u16* __restrict__ aout)
{
  __shared__ __align__(16) char lds[131072];
  char* kl = lds;
  char* vl = lds + 16384;
  const int tid = threadIdx.x;
  const int lane = tid & 63, wid = tid >> 6;
  const int lo = lane & 31, hi = lane >> 5;
  char* wl = lds + 32768 + wid*8192;
  char* pl = lds + 98304 + wid*4096;

  // XCD swizzle: XCD (g&7) owns heads [4x, 4x+4) -> ~2MB K/V per XCD L2
  const int g = blockIdx.x;             // [0,256)
  const int j = g >> 3;                 // [0,32)
  const int bh = (g & 7)*4 + (j >> 3);  // 4 heads per XCD
  const int qblk = j & 7;               // 8 q-blocks of 256 rows
  const int b = bh >> 4;
  const int q0 = qblk*256 + wid*32;

  const u16* qb = qp + ((size_t)bh*NQL + q0)*64;
  const u16* kb = kp + (size_t)bh*NKL*64;
  const u16* vb = vt + (size_t)bh*64*NKL;
  const float* wb = wts + ((size_t)bh*NQL + q0)*(size_t)NKL;

  // Q fragments (A-operand): row q = lo, d-slice ks*16 + hi*8
  short8 qf[4];
  #pragma unroll
  for (int ks=0;ks<4;ks++)
    qf[ks] = *(const short8*)(qb + (size_t)lo*64 + ks*16 + hi*8);

  f32x16 o0, o1;
  float ls[16];
  #pragma unroll
  for (int r=0;r<16;r++){ o0[r]=0.f; o1[r]=0.f; ls[r]=0.f; }

  // K/V staging (512 threads, 1 gload16 each per tensor):
  // K: row = tid>>3 in [0,64), slot8 = tid&7, swizzle key (row>>1)&7
  // V: d-row = tid>>3, swizzle key row&7
  const int krow = tid >> 3, ksl = tid & 7;
  const int le16 = lane & 15, ld16 = lane >> 4;   // W staging (per-wave slab)

  // ---- prologue: stage tile 0 ----
  {
    gload16(kb + (size_t)krow*64 + (ksl ^ ((krow>>1)&7))*8, kl + tid*16);
    gload16(vb + (size_t)krow*NKL + (ksl ^ (krow&7))*8,     vl + tid*16);
    #pragma unroll
    for (int i=0;i<8;i++){
      int q = 4*i + ld16;
      gload16nt(wb + (size_t)q*NKL + le16*4, wl + i*1024);
    }
  }
  __syncthreads();

  for (int kt=0; kt<32; kt++){
    const int cur = (kt&1)*8192;
    const int nxt = cur ^ 8192;
    const int kb0 = kt*64;

    // K/V prefetch first: targets nxt buffer, earliest issue
    if (kt < 31){
      int kb1 = kb0 + 64;
      gload16(kb + (size_t)(kb1+krow)*64 + (ksl ^ ((krow>>1)&7))*8, kl + nxt + tid*16);
      gload16(vb + (size_t)krow*NKL + kb1 + (ksl ^ (krow&7))*8,     vl + nxt + tid*16);
    }

    // W[cur] -> regs (per-wave slab; must drain before overwrite-prefetch)
    f32x2 wp[16];
    #pragma unroll
    for (int r=0;r<16;r++){
      int qr = (r&3) + 8*(r>>2) + 4*hi;
      wp[r] = *(const f32x2*)(wl + qr*256 + lo*8);
    }
    // K fragments from swizzled LDS: rows 2lo (kf0), 2lo+1 (kf1)
    short8 kf0[4], kf1[4];
    #pragma unroll
    for (int ks=0;ks<4;ks++){
      int slot = (ks*2 + hi) ^ (lo&7);
      kf0[ks] = *(const short8*)(kl + cur + (2*lo)*128 + slot*16);
      kf1[ks] = *(const short8*)(kl + cur + (2*lo)*128 + 128 + slot*16);
    }
    asm volatile("s_waitcnt lgkmcnt(0)" ::: "memory");
    __builtin_amdgcn_sched_barrier(0);

    // W prefetch (overwrites slab just read) - NT stream
    if (kt < 31){
      int kb1 = kb0 + 64;
      #pragma unroll
      for (int i=0;i<8;i++){
        int q = 4*i + ld16;
        gload16nt(wb + (size_t)q*NKL + kb1 + le16*4, wl + i*1024);
      }
    }

    // QK^T
    f32x16 s0, s1;
    #pragma unroll
    for (int r=0;r<16;r++){ s0[r]=0.f; s1[r]=0.f; }
    #pragma unroll
    for (int ks=0;ks<4;ks++){
      s0 = MFMA32(qf[ks], kf0[ks], s0);
      s1 = MFMA32(qf[ks], kf1[ks], s1);
    }

    // V fragments from swizzled LDS: rows d=lo (vf0), d=32+lo (vf1)
    short8 vf0[4], vf1[4];
    #pragma unroll
    for (int t=0;t<4;t++){
      int slot = (t*2 + hi) ^ (lo&7);
      vf0[t] = *(const short8*)(vl + cur + lo*128 + slot*16);
      vf1[t] = *(const short8*)(vl + cur + (32+lo)*128 + slot*16);
    }

    // flat softmax: p = exp2(s*w); pack to bf16 P tile (swizzled)
    #pragma unroll
    for (int r=0;r<16;r++){
      float p0 = exp2f(s0[r] * wp[r].x);
      float p1 = exp2f(s1[r] * wp[r].y);
      ls[r] += p0 + p1;
      u32 pk;
      asm("v_cvt_pk_bf16_f32 %0, %1, %2" : "=v"(pk) : "v"(p0), "v"(p1));
      int row = (r&3) + 8*(r>>2) + 4*hi;
      *(u32*)(pl + row*128 + ((lo*4) ^ ((row&7)<<4))) = pk;
    }
    asm volatile("s_waitcnt lgkmcnt(0)" ::: "memory");
    // P fragments (A-operand): row q = lo
    short8 pf[4];
    #pragma unroll
    for (int t=0;t<4;t++)
      pf[t] = *(const short8*)(pl + lo*128 + ((t*32 + hi*16) ^ ((lo&7)<<4)));
    #pragma unroll
    for (int t=0;t<4;t++){
      o0 = MFMA32(pf[t], vf0[t], o0);
      o1 = MFMA32(pf[t], vf1[t], o1);
    }
    __syncthreads();   // drains vmcnt (staged tiles) + barrier
  }

  // epilogue: rowsum reduce, divide, store bf16
  u16* ob = aout + ((size_t)b*NQL + q0)*DM + (bh & 15)*64;
  #pragma unroll
  for (int r=0;r<16;r++){
    float L = ls[r];
    L += __shfl_xor(L,1); L += __shfl_xor(L,2); L += __shfl_xor(L,4);
    L += __shfl_xor(L,8); L += __shfl_xor(L,16);
    float inv = 1.0f / L;
    int q = (r&3) + 8*(r>>2) + 4*hi;
    ob[(size_t)q*DM + lo]      = f2bf(o0[r]*inv);
    ob[(size_t)q*DM + 32 + lo] = f2bf(o1[r]*inv);
  }
}

// ---------------- launcher ----------------
extern "C" void kernel_launch(void* const* d_in, const int* in_sizes, int n_in,
                              void* d_out, int out_size, void* d_ws, size_t ws_size,
                              hipStream_t stream){
  const float* queries = (const float*)d_in[0];
  const float* keys    = (const float*)d_in[1];
  const float* values  = (const float*)d_in[2];
  const float* attw    = (const float*)d_in[3];
  const float* Wq = (const float*)d_in[4];
  const float* bq = (const float*)d_in[5];
  const float* Wk = (const float*)d_in[6];
  const float* bk = (const float*)d_in[7];
  const float* Wv = (const float*)d_in[8];
  const float* bv = (const float*)d_in[9];
  const float* Wo = (const float*)d_in[10];
  const float* bo = (const float*)d_in[11];
  char* ws = (char*)d_ws;
  u16* abf   = (u16*)(ws + OFF_ABF);
  u16* btqkv = (u16*)(ws + OFF_BTQKV);
  u16* bto   = (u16*)(ws + OFF_BTO);
  u16* qp    = (u16*)(ws + OFF_QP);
  u16* kp    = (u16*)(ws + OFF_KP);
  u16* vt    = (u16*)(ws + OFF_VT);
  u16* aout  = (u16*)(ws + OFF_AOUT);
  float* out = (float*)d_out;

  cast3_kernel<<<12288, 256, 0, stream>>>(queries, keys, values, abf);
  twcast_kernel<<<dim3(32,32,4), dim3(32,8), 0, stream>>>(Wq,Wk,Wv,Wo,btqkv,bto);
  gemm0_kernel<<<dim3(24,32), 256, 0, stream>>>(abf, btqkv, bq,bk,bv, qp,kp,vt);
  attn_kernel<<<256, 512, 0, stream>>>(qp, kp, vt, attw, aout);
  gemm1_kernel<<<dim3(8,64), 256, 0, stream>>>(aout, bto, bo, out);
}